// Round 9
// baseline (235.184 us; speedup 1.0000x reference)
//
#include <hip/hip_runtime.h>
#include <hip/hip_cooperative_groups.h>

#define IN_F 256
#define OUT_F 64
#define NBKT_MAX 1024          // buckets of 64 dst nodes; supports N <= 65536
#define PARTB 64               // partition worker blocks: run = E/(PARTB*NB) edges
#define HIST_BLOCKS 256
#define PREP_BLOCKS 256

namespace cg = cooperative_groups;

typedef __attribute__((ext_vector_type(8))) short short8;
typedef __attribute__((ext_vector_type(4))) float f32x4;
typedef unsigned int uint32;

#define AS_I(f) __builtin_bit_cast(int, f)
#define AS_F(i) __builtin_bit_cast(float, i)
#define DPP_ADD(v, ctrl, rmask) \
    v += AS_F(__builtin_amdgcn_update_dpp(0, AS_I(v), ctrl, rmask, 0xf, true))

// Per-half (32-lane) sum: row_shr 1/2/4/8 + row_bcast:15 -> lane31 = low-half
// sum, lane63 = high-half sum. Select by half.
__device__ __forceinline__ float half_sum_sel(float p, bool hi) {
    DPP_ADD(p, 0x111, 0xf);
    DPP_ADD(p, 0x112, 0xf);
    DPP_ADD(p, 0x114, 0xf);
    DPP_ADD(p, 0x118, 0xf);
    DPP_ADD(p, 0x142, 0xa);
    float dlo = AS_F(__builtin_amdgcn_readlane(AS_I(p), 31));
    float dhi = AS_F(__builtin_amdgcn_readlane(AS_I(p), 63));
    return hi ? dhi : dlo;
}

__device__ __forceinline__ unsigned short f2bf(float f) {  // RNE f32->bf16
    uint32 u = __builtin_bit_cast(uint32, f);
    u += 0x7fffu + ((u >> 16) & 1u);
    return (unsigned short)(u >> 16);
}
__device__ __forceinline__ float bf2f(unsigned short s) {
    return __builtin_bit_cast(float, (uint32)s << 16);
}

// ---------------------------------------------------------------------------
// FUSED: blocks [0,ngemm) = MFMA gemm (w staged as bf16 B-frags in LDS);
// blocks [ngemm, ngemm+HIST_BLOCKS) = LDS-staged bucket histogram.
// ---------------------------------------------------------------------------
__global__ __launch_bounds__(256) void gemm_hist_kernel(const float* __restrict__ h,
                                                        const float* __restrict__ w,
                                                        unsigned short* __restrict__ hpb,
                                                        int N,
                                                        const int* __restrict__ dst,
                                                        int* __restrict__ bkt_cnt,
                                                        int E, int NB, int ngemm) {
    __shared__ char smem[32768];          // union: wfrag (gemm) / lcnt (hist)
    int b = blockIdx.x, t = threadIdx.x;

    if (b >= ngemm) {
        int* lcnt = (int*)smem;
        int hb = b - ngemm;
        for (int i = t; i < NB; i += 256) lcnt[i] = 0;
        __syncthreads();
        for (int e = hb * 256 + t; e < E; e += HIST_BLOCKS * 256)
            atomicAdd(&lcnt[dst[e] >> 6], 1);
        __syncthreads();
        for (int i = t; i < NB; i += 256)
            if (lcnt[i]) atomicAdd(&bkt_cnt[i], lcnt[i]);
        return;
    }

    short8* wfrag = (short8*)smem;        // 2048 slots * 16B = 32 KB
    for (int slot = t; slot < 2048; slot += 256) {
        int kb = slot >> 6, n = slot & 63;
        short8 v;
#pragma unroll
        for (int jj = 0; jj < 8; ++jj)
            v[jj] = (short)f2bf(w[(size_t)(kb * 8 + jj) * OUT_F + n]);
        wfrag[slot] = v;
    }
    __syncthreads();

    int wave = t >> 6, lane = t & 63;
    int n16  = lane & 15, quad = lane >> 4;
    int base = b * 64 + wave * 16;
    int arow_i = base + n16; if (arow_i >= N) arow_i = N - 1;
    const float* arow = h + (size_t)arow_i * IN_F;

    f32x4 acc[4];
#pragma unroll
    for (int ct = 0; ct < 4; ++ct) acc[ct] = (f32x4){0.f, 0.f, 0.f, 0.f};

#pragma unroll
    for (int ks = 0; ks < 8; ++ks) {
        int k0 = ks * 32;
        float4 a0 = *(const float4*)(arow + k0 + quad * 8);
        float4 a1 = *(const float4*)(arow + k0 + quad * 8 + 4);
        short8 af;
        af[0] = (short)f2bf(a0.x); af[1] = (short)f2bf(a0.y);
        af[2] = (short)f2bf(a0.z); af[3] = (short)f2bf(a0.w);
        af[4] = (short)f2bf(a1.x); af[5] = (short)f2bf(a1.y);
        af[6] = (short)f2bf(a1.z); af[7] = (short)f2bf(a1.w);
        int kb = ks * 4 + quad;
#pragma unroll
        for (int ct = 0; ct < 4; ++ct) {
            short8 bf = wfrag[kb * 64 + ct * 16 + n16];
            acc[ct] = __builtin_amdgcn_mfma_f32_16x16x32_bf16(af, bf, acc[ct], 0, 0, 0);
        }
    }

#pragma unroll
    for (int ct = 0; ct < 4; ++ct) {
#pragma unroll
        for (int r = 0; r < 4; ++r) {
            int ro = base + quad * 4 + r;
            if (ro < N) hpb[(size_t)ro * OUT_F + ct * 16 + n16] = f2bf(acc[ct][r]);
        }
    }
}

// ---------------------------------------------------------------------------
// Cooperative prep: A) every block redundantly scans bkt_cnt -> LDS sbase;
// B) first PARTB blocks partition edges into bucket-grouped packed pairs
//    (per-(chunk,bucket) runs of ~16 edges = 64B = full line);
// grid.sync;
// C) per-bucket LDS counting sort -> node-sorted srcs + node-level row_ptr.
// ---------------------------------------------------------------------------
__global__ __launch_bounds__(256) void prep_kernel(const int* __restrict__ src,
                                                   const int* __restrict__ dst,
                                                   const int* __restrict__ bkt_cnt,
                                                   int* __restrict__ bkt_cursor,
                                                   uint32* __restrict__ pairs,
                                                   int* __restrict__ srcs,
                                                   int* __restrict__ row_ptr,
                                                   int N, int E, int NB) {
    __shared__ int sbase[NBKT_MAX + 1];
    __shared__ int lcnt[NBKT_MAX];
    __shared__ int gbase[NBKT_MAX];
    __shared__ int wsum2[4];
    __shared__ int bin[64], excl[65], cur[64];

    int t = threadIdx.x, lane = t & 63, wid = t >> 6;

    // ---- Phase A: redundant exclusive scan of bkt_cnt (4 values/thread) ----
    int loc[4];
    int s = 0;
#pragma unroll
    for (int j = 0; j < 4; ++j) {
        int idx = t * 4 + j;
        int x = (idx < NB) ? bkt_cnt[idx] : 0;
        loc[j] = s; s += x;
    }
    int xs = s;
#pragma unroll
    for (int off = 1; off < 64; off <<= 1) {
        int y = __shfl_up(xs, off, 64);
        if (lane >= off) xs += y;
    }
    if (lane == 63) wsum2[wid] = xs;
    __syncthreads();
    int base_w = 0;
    for (int k = 0; k < wid; ++k) base_w += wsum2[k];
    int toff = base_w + xs - s;
#pragma unroll
    for (int j = 0; j < 4; ++j) {
        int idx = t * 4 + j;
        if (idx < NB) sbase[idx] = toff + loc[j];
    }
    if (t == 0) sbase[NB] = E;
    __syncthreads();

    // ---- Phase B: partition (first PARTB blocks only) ----
    if (blockIdx.x < PARTB) {
        int chunk = (E + PARTB - 1) / PARTB;
        int s0 = blockIdx.x * chunk;
        int s1 = min(E, s0 + chunk);

        for (int i = t; i < NB; i += 256) lcnt[i] = 0;
        __syncthreads();
        for (int e = s0 + t; e < s1; e += 256)
            atomicAdd(&lcnt[dst[e] >> 6], 1);
        __syncthreads();
        for (int i = t; i < NB; i += 256) {
            int c = lcnt[i];
            if (c) gbase[i] = sbase[i] + atomicAdd(&bkt_cursor[i], c);
            lcnt[i] = 0;
        }
        __syncthreads();
        for (int e = s0 + t; e < s1; e += 256) {
            int d  = dst[e];
            int bk = d >> 6;
            int idx = atomicAdd(&lcnt[bk], 1);
            pairs[gbase[bk] + idx] = (uint32)src[e] | ((uint32)(d & 63) << 26);
        }
    }

    cg::this_grid().sync();

    // ---- Phase C: per-bucket counting sort (buckets strided over blocks) ----
    for (int b = blockIdx.x; b < NB; b += gridDim.x) {
        int beg = sbase[b], end = sbase[b + 1];

        if (t < 64) bin[t] = 0;
        __syncthreads();
        for (int i = beg + t; i < end; i += 256)
            atomicAdd(&bin[pairs[i] >> 26], 1);
        __syncthreads();
        if (t < 64) {
            int v = bin[t], x = v;
#pragma unroll
            for (int off = 1; off < 64; off <<= 1) {
                int y = __shfl_up(x, off, 64);
                if (t >= off) x += y;
            }
            excl[t] = x - v;
            cur[t]  = x - v;
            if (t == 63) excl[64] = x;
        }
        __syncthreads();
        if (t < 65) {
            int idx = b * 64 + t;
            if (idx <= N) row_ptr[idx] = beg + excl[t];
        }
        for (int i = beg + t; i < end; i += 256) {
            uint32 p = pairs[i];
            int dl   = (int)(p >> 26);
            int pos  = atomicAdd(&cur[dl], 1);
            srcs[beg + pos] = (int)(p & 0x3FFFFFFu);
        }
        __syncthreads();   // before bin reuse in next bucket
    }
}

// ---------------------------------------------------------------------------
// Accumulate: one wave per dst node; lanes 0-31 = edge j, 32-63 = edge j+1,
// lane carries 2 bf16 features -> one dword gather serves two edge rows.
// 8 loads in flight = 16 edges MLP; DPP per-half reduce; register accumulate.
// ---------------------------------------------------------------------------
__global__ __launch_bounds__(256) void accum_kernel(const unsigned short* __restrict__ hpb,
                                                    const int* __restrict__ row_ptr,
                                                    const int* __restrict__ srcs,
                                                    const float* __restrict__ attw,
                                                    float* __restrict__ out, int N) {
    int v    = (blockIdx.x * blockDim.x + threadIdx.x) >> 6;
    int lane = threadIdx.x & 63;
    if (v >= N) return;

    int  half = lane & 31;
    bool hi   = lane >= 32;

    int beg = row_ptr[v];
    int end = row_ptr[v + 1];

    uint32 hd2 = *(const uint32*)(hpb + (size_t)v * OUT_F + half * 2);
    float hd0 = bf2f((unsigned short)(hd2 & 0xffff));
    float hd1 = bf2f((unsigned short)(hd2 >> 16));

    float c = 0.f;
#pragma unroll
    for (int i = 0; i < 8; ++i) c += attw[i];

    float acc0 = 0.f, acc1 = 0.f;
    int j = beg;

    for (; j + 16 <= end; j += 16) {
        int4 s4[4];
#pragma unroll
        for (int u = 0; u < 4; ++u) s4[u] = ((const int4*)(srcs + j))[u];
        int slo[8], shi[8];
#pragma unroll
        for (int u = 0; u < 4; ++u) {
            slo[2 * u]     = s4[u].x; shi[2 * u]     = s4[u].y;
            slo[2 * u + 1] = s4[u].z; shi[2 * u + 1] = s4[u].w;
        }
        uint32 a2[8];
#pragma unroll
        for (int u = 0; u < 8; ++u) {
            int s = hi ? shi[u] : slo[u];
            a2[u] = *(const uint32*)(hpb + (size_t)s * OUT_F + half * 2);
        }
        float a0[8], a1[8], d[8];
#pragma unroll
        for (int u = 0; u < 8; ++u) {
            a0[u] = bf2f((unsigned short)(a2[u] & 0xffff));
            a1[u] = bf2f((unsigned short)(a2[u] >> 16));
            d[u]  = half_sum_sel(fmaf(a1[u], hd1, a0[u] * hd0), hi);
        }
#pragma unroll
        for (int u = 0; u < 8; ++u) {
            acc0 = fmaf(d[u], a0[u], acc0);
            acc1 = fmaf(d[u], a1[u], acc1);
        }
    }
    for (; j + 2 <= end; j += 2) {
        int s_lo = srcs[j], s_hi = srcs[j + 1];
        int s = hi ? s_hi : s_lo;
        uint32 a2 = *(const uint32*)(hpb + (size_t)s * OUT_F + half * 2);
        float a0 = bf2f((unsigned short)(a2 & 0xffff));
        float a1 = bf2f((unsigned short)(a2 >> 16));
        float d  = half_sum_sel(fmaf(a1, hd1, a0 * hd0), hi);
        acc0 = fmaf(d, a0, acc0);
        acc1 = fmaf(d, a1, acc1);
    }
    if (j < end) {                          // odd final edge
        int s = srcs[j];
        uint32 a2 = *(const uint32*)(hpb + (size_t)s * OUT_F + half * 2);
        float a0 = bf2f((unsigned short)(a2 & 0xffff));
        float a1 = bf2f((unsigned short)(a2 >> 16));
        float d  = half_sum_sel(fmaf(a1, hd1, a0 * hd0), false);
        if (!hi) {
            acc0 = fmaf(d, a0, acc0);
            acc1 = fmaf(d, a1, acc1);
        }
    }

    acc0 += __shfl_xor(acc0, 32, 64);
    acc1 += __shfl_xor(acc1, 32, 64);

    if (!hi) {
        float r0, r1;
        if (end > beg) { r0 = acc0 * c; r1 = acc1 * c; }
        else           { r0 = hd0;      r1 = hd1;      }
        *(float2*)(out + (size_t)v * OUT_F + half * 2) = make_float2(r0, r1);
    }
}

extern "C" void kernel_launch(void* const* d_in, const int* in_sizes, int n_in,
                              void* d_out, int out_size, void* d_ws, size_t ws_size,
                              hipStream_t stream) {
    const float* h    = (const float*)d_in[0];
    const float* w    = (const float*)d_in[1];
    const float* attw = (const float*)d_in[2];
    const int*   src  = (const int*)d_in[3];
    const int*   dst  = (const int*)d_in[4];

    int N = in_sizes[0] / IN_F;
    int E = in_sizes[3];
    int NB = (N + 63) >> 6;    // 782 for N=50000 (NB <= NBKT_MAX)
    int ngemm = (N + 63) / 64;

    float* out = (float*)d_out;

    char* p = (char*)d_ws;
    unsigned short* hpb = (unsigned short*)p;  p += (size_t)N * OUT_F * sizeof(unsigned short);
    int* bkt_cnt    = (int*)p;                 p += (NBKT_MAX + 1) * sizeof(int);
    int* bkt_cursor = (int*)p;                 p += (NBKT_MAX + 1) * sizeof(int);
    int* row_ptr    = (int*)p;                 p += ((size_t)N + 8) * sizeof(int);
    uint32* pairs   = (uint32*)p;              p += (size_t)E * sizeof(uint32);
    int* srcs       = (int*)p;

    // zero bkt_cnt + bkt_cursor in one shot (contiguous)
    hipMemsetAsync(bkt_cnt, 0, 2 * (NBKT_MAX + 1) * sizeof(int), stream);

    gemm_hist_kernel<<<ngemm + HIST_BLOCKS, 256, 0, stream>>>(h, w, hpb, N,
                                                              dst, bkt_cnt, E, NB, ngemm);

    {
        void* src_v  = (void*)src;
        void* dst_v  = (void*)dst;
        void* cnt_v  = (void*)bkt_cnt;
        void* cur_v  = (void*)bkt_cursor;
        void* pr_v   = (void*)pairs;
        void* srcs_v = (void*)srcs;
        void* rp_v   = (void*)row_ptr;
        void* args[] = { &src_v, &dst_v, &cnt_v, &cur_v, &pr_v, &srcs_v, &rp_v,
                         &N, &E, &NB };
        hipLaunchCooperativeKernel((const void*)prep_kernel, dim3(PREP_BLOCKS),
                                   dim3(256), args, 0, stream);
    }

    accum_kernel<<<((size_t)N * 64 + 255) / 256, 256, 0, stream>>>(hpb, row_ptr, srcs, attw, out, N);
}

// Round 10
// 197.659 us; speedup vs baseline: 1.1898x; 1.1898x over previous
//
#include <hip/hip_runtime.h>

#define IN_F 256
#define OUT_F 64
#define NBKT_MAX 1024          // buckets of 64 dst nodes; supports N <= 65536
#define PART_BLOCKS 128
#define HIST_BLOCKS 256

typedef __attribute__((ext_vector_type(8))) short short8;
typedef __attribute__((ext_vector_type(4))) float f32x4;
typedef unsigned int uint32;

#define AS_I(f) __builtin_bit_cast(int, f)
#define AS_F(i) __builtin_bit_cast(float, i)
#define DPP_ADD(v, ctrl, rmask) \
    v += AS_F(__builtin_amdgcn_update_dpp(0, AS_I(v), ctrl, rmask, 0xf, true))

// Per-half (32-lane) sum: row_shr 1/2/4/8 + row_bcast:15 -> lane31 = low-half
// sum, lane63 = high-half sum. Select by half. Pure VALU pipe (DPP).
__device__ __forceinline__ float half_sum_sel(float p, bool hi) {
    DPP_ADD(p, 0x111, 0xf);
    DPP_ADD(p, 0x112, 0xf);
    DPP_ADD(p, 0x114, 0xf);
    DPP_ADD(p, 0x118, 0xf);
    DPP_ADD(p, 0x142, 0xa);
    float dlo = AS_F(__builtin_amdgcn_readlane(AS_I(p), 31));
    float dhi = AS_F(__builtin_amdgcn_readlane(AS_I(p), 63));
    return hi ? dhi : dlo;
}

__device__ __forceinline__ unsigned short f2bf(float f) {  // RNE f32->bf16
    uint32 u = __builtin_bit_cast(uint32, f);
    u += 0x7fffu + ((u >> 16) & 1u);
    return (unsigned short)(u >> 16);
}
__device__ __forceinline__ float bf2f(unsigned short s) {
    return __builtin_bit_cast(float, (uint32)s << 16);
}

// ---------------------------------------------------------------------------
// FUSED: blocks [0,ngemm) = MFMA gemm (w staged as bf16 B-frags in LDS);
// blocks [ngemm, ngemm+HIST_BLOCKS) = LDS-staged bucket histogram.
// ---------------------------------------------------------------------------
__global__ __launch_bounds__(256) void gemm_hist_kernel(const float* __restrict__ h,
                                                        const float* __restrict__ w,
                                                        unsigned short* __restrict__ hpb,
                                                        int N,
                                                        const int* __restrict__ dst,
                                                        int* __restrict__ bkt_cnt,
                                                        int E, int NB, int ngemm) {
    __shared__ char smem[32768];          // union: wfrag (gemm) / lcnt (hist)
    int b = blockIdx.x, t = threadIdx.x;

    if (b >= ngemm) {
        int* lcnt = (int*)smem;
        int hb = b - ngemm;
        for (int i = t; i < NB; i += 256) lcnt[i] = 0;
        __syncthreads();
        for (int e = hb * 256 + t; e < E; e += HIST_BLOCKS * 256)
            atomicAdd(&lcnt[dst[e] >> 6], 1);
        __syncthreads();
        for (int i = t; i < NB; i += 256)
            if (lcnt[i]) atomicAdd(&bkt_cnt[i], lcnt[i]);
        return;
    }

    short8* wfrag = (short8*)smem;        // 2048 slots * 16B = 32 KB
    for (int slot = t; slot < 2048; slot += 256) {
        int kb = slot >> 6, n = slot & 63;
        short8 v;
#pragma unroll
        for (int jj = 0; jj < 8; ++jj)
            v[jj] = (short)f2bf(w[(size_t)(kb * 8 + jj) * OUT_F + n]);
        wfrag[slot] = v;
    }
    __syncthreads();

    int wave = t >> 6, lane = t & 63;
    int n16  = lane & 15, quad = lane >> 4;
    int base = b * 64 + wave * 16;
    int arow_i = base + n16; if (arow_i >= N) arow_i = N - 1;
    const float* arow = h + (size_t)arow_i * IN_F;

    f32x4 acc[4];
#pragma unroll
    for (int ct = 0; ct < 4; ++ct) acc[ct] = (f32x4){0.f, 0.f, 0.f, 0.f};

#pragma unroll
    for (int ks = 0; ks < 8; ++ks) {
        int k0 = ks * 32;
        float4 a0 = *(const float4*)(arow + k0 + quad * 8);
        float4 a1 = *(const float4*)(arow + k0 + quad * 8 + 4);
        short8 af;
        af[0] = (short)f2bf(a0.x); af[1] = (short)f2bf(a0.y);
        af[2] = (short)f2bf(a0.z); af[3] = (short)f2bf(a0.w);
        af[4] = (short)f2bf(a1.x); af[5] = (short)f2bf(a1.y);
        af[6] = (short)f2bf(a1.z); af[7] = (short)f2bf(a1.w);
        int kb = ks * 4 + quad;
#pragma unroll
        for (int ct = 0; ct < 4; ++ct) {
            short8 bf = wfrag[kb * 64 + ct * 16 + n16];
            acc[ct] = __builtin_amdgcn_mfma_f32_16x16x32_bf16(af, bf, acc[ct], 0, 0, 0);
        }
    }

#pragma unroll
    for (int ct = 0; ct < 4; ++ct) {
#pragma unroll
        for (int r = 0; r < 4; ++r) {
            int ro = base + quad * 4 + r;
            if (ro < N) hpb[(size_t)ro * OUT_F + ct * 16 + n16] = f2bf(acc[ct][r]);
        }
    }
}

// ---------------------------------------------------------------------------
// Partition (128 blocks): A) each block redundantly scans bkt_cnt -> LDS
// sbase (block 0 also publishes it as global bkt_base for sortlocal);
// B) LDS-count own chunk -> ONE cursor atomic per (block,bucket) ->
// contiguous runs of packed (dstLocal<<26 | src).
// ---------------------------------------------------------------------------
__global__ __launch_bounds__(256) void partition_kernel(const int* __restrict__ src,
                                                        const int* __restrict__ dst,
                                                        const int* __restrict__ bkt_cnt,
                                                        int* __restrict__ bkt_cursor,
                                                        int* __restrict__ bkt_base,
                                                        uint32* __restrict__ pairs,
                                                        int E, int NB) {
    __shared__ int sbase[NBKT_MAX + 1];
    __shared__ int lcnt[NBKT_MAX];
    __shared__ int gbase[NBKT_MAX];
    __shared__ int wsum2[4];

    int t = threadIdx.x, lane = t & 63, wid = t >> 6;

    // ---- Phase A: redundant exclusive scan of bkt_cnt (4 values/thread) ----
    int loc[4];
    int s = 0;
#pragma unroll
    for (int j = 0; j < 4; ++j) {
        int idx = t * 4 + j;
        int x = (idx < NB) ? bkt_cnt[idx] : 0;
        loc[j] = s; s += x;
    }
    int xs = s;
#pragma unroll
    for (int off = 1; off < 64; off <<= 1) {
        int y = __shfl_up(xs, off, 64);
        if (lane >= off) xs += y;
    }
    if (lane == 63) wsum2[wid] = xs;
    __syncthreads();
    int base_w = 0;
    for (int k = 0; k < wid; ++k) base_w += wsum2[k];
    int toff = base_w + xs - s;
#pragma unroll
    for (int j = 0; j < 4; ++j) {
        int idx = t * 4 + j;
        if (idx < NB) sbase[idx] = toff + loc[j];
    }
    if (t == 0) sbase[NB] = E;
    __syncthreads();

    if (blockIdx.x == 0) {
        for (int i = t; i <= NB; i += 256) bkt_base[i] = sbase[i];
    }

    // ---- Phase B: partition own chunk ----
    int chunk = (E + PART_BLOCKS - 1) / PART_BLOCKS;
    int s0 = blockIdx.x * chunk;
    int s1 = min(E, s0 + chunk);

    for (int i = t; i < NB; i += 256) lcnt[i] = 0;
    __syncthreads();
    for (int e = s0 + t; e < s1; e += 256)
        atomicAdd(&lcnt[dst[e] >> 6], 1);
    __syncthreads();
    for (int i = t; i < NB; i += 256) {
        int c = lcnt[i];
        if (c) gbase[i] = sbase[i] + atomicAdd(&bkt_cursor[i], c);
        lcnt[i] = 0;
    }
    __syncthreads();
    for (int e = s0 + t; e < s1; e += 256) {
        int d  = dst[e];
        int bk = d >> 6;
        int idx = atomicAdd(&lcnt[bk], 1);
        pairs[gbase[bk] + idx] = (uint32)src[e] | ((uint32)(d & 63) << 26);
    }
}

// ---------------------------------------------------------------------------
// Per-bucket LDS counting sort: bucket-sorted pairs -> node-sorted srcs +
// node-level row_ptr. Writes stay in the block's own ~4KB region (L2-hot).
// ---------------------------------------------------------------------------
__global__ __launch_bounds__(256) void sortlocal_kernel(const uint32* __restrict__ pairs,
                                                        const int* __restrict__ bkt_base,
                                                        int* __restrict__ srcs,
                                                        int* __restrict__ row_ptr,
                                                        int N, int E) {
    __shared__ int bin[64], excl[65], cur[64];
    int b = blockIdx.x, t = threadIdx.x;
    int beg = bkt_base[b], end = bkt_base[b + 1];

    if (t < 64) bin[t] = 0;
    __syncthreads();
    for (int i = beg + t; i < end; i += 256)
        atomicAdd(&bin[pairs[i] >> 26], 1);
    __syncthreads();
    if (t < 64) {
        int v = bin[t], x = v;
#pragma unroll
        for (int off = 1; off < 64; off <<= 1) {
            int y = __shfl_up(x, off, 64);
            if (t >= off) x += y;
        }
        excl[t] = x - v;
        cur[t]  = x - v;
        if (t == 63) excl[64] = x;
    }
    __syncthreads();
    if (t < 65) {
        int idx = b * 64 + t;
        if (idx <= N) row_ptr[idx] = beg + excl[t];
    }
    for (int i = beg + t; i < end; i += 256) {
        uint32 p = pairs[i];
        int dl   = (int)(p >> 26);
        int pos  = atomicAdd(&cur[dl], 1);
        srcs[beg + pos] = (int)(p & 0x3FFFFFFu);
    }
}

// ---------------------------------------------------------------------------
// Accumulate: one wave per dst node; lanes 0-31 = even edge, 32-63 = odd edge,
// lane carries 2 bf16 features -> one dword gather serves two edge rows.
// Main loop: 16 gathers in flight = 32 edges MLP. DPP per-half reduce.
// ---------------------------------------------------------------------------
__global__ __launch_bounds__(256) void accum_kernel(const unsigned short* __restrict__ hpb,
                                                    const int* __restrict__ row_ptr,
                                                    const int* __restrict__ srcs,
                                                    const float* __restrict__ attw,
                                                    float* __restrict__ out, int N) {
    int v    = (blockIdx.x * blockDim.x + threadIdx.x) >> 6;
    int lane = threadIdx.x & 63;
    if (v >= N) return;

    int  half = lane & 31;
    bool hi   = lane >= 32;

    int beg = row_ptr[v];
    int end = row_ptr[v + 1];

    uint32 hd2 = *(const uint32*)(hpb + (size_t)v * OUT_F + half * 2);
    float hd0 = bf2f((unsigned short)(hd2 & 0xffff));
    float hd1 = bf2f((unsigned short)(hd2 >> 16));

    float c = 0.f;
#pragma unroll
    for (int i = 0; i < 8; ++i) c += attw[i];

    float acc0 = 0.f, acc1 = 0.f;
    int j = beg;

    for (; j + 32 <= end; j += 32) {        // 16 pair-gathers = 32 edges in flight
        int4 s4[8];
#pragma unroll
        for (int u = 0; u < 8; ++u) s4[u] = ((const int4*)(srcs + j))[u];
        uint32 a2[16];
#pragma unroll
        for (int u = 0; u < 8; ++u) {
            int sA = hi ? s4[u].y : s4[u].x;
            int sB = hi ? s4[u].w : s4[u].z;
            a2[2 * u]     = *(const uint32*)(hpb + (size_t)sA * OUT_F + half * 2);
            a2[2 * u + 1] = *(const uint32*)(hpb + (size_t)sB * OUT_F + half * 2);
        }
#pragma unroll
        for (int u = 0; u < 16; ++u) {
            float a0 = bf2f((unsigned short)(a2[u] & 0xffff));
            float a1 = bf2f((unsigned short)(a2[u] >> 16));
            float d  = half_sum_sel(fmaf(a1, hd1, a0 * hd0), hi);
            acc0 = fmaf(d, a0, acc0);
            acc1 = fmaf(d, a1, acc1);
        }
    }
    for (; j + 16 <= end; j += 16) {        // 8 pair-gathers = 16 edges
        int4 s4[4];
#pragma unroll
        for (int u = 0; u < 4; ++u) s4[u] = ((const int4*)(srcs + j))[u];
        uint32 a2[8];
#pragma unroll
        for (int u = 0; u < 4; ++u) {
            int sA = hi ? s4[u].y : s4[u].x;
            int sB = hi ? s4[u].w : s4[u].z;
            a2[2 * u]     = *(const uint32*)(hpb + (size_t)sA * OUT_F + half * 2);
            a2[2 * u + 1] = *(const uint32*)(hpb + (size_t)sB * OUT_F + half * 2);
        }
#pragma unroll
        for (int u = 0; u < 8; ++u) {
            float a0 = bf2f((unsigned short)(a2[u] & 0xffff));
            float a1 = bf2f((unsigned short)(a2[u] >> 16));
            float d  = half_sum_sel(fmaf(a1, hd1, a0 * hd0), hi);
            acc0 = fmaf(d, a0, acc0);
            acc1 = fmaf(d, a1, acc1);
        }
    }
    for (; j + 2 <= end; j += 2) {          // leftover pairs
        int s_lo = srcs[j], s_hi = srcs[j + 1];
        int s = hi ? s_hi : s_lo;
        uint32 a2 = *(const uint32*)(hpb + (size_t)s * OUT_F + half * 2);
        float a0 = bf2f((unsigned short)(a2 & 0xffff));
        float a1 = bf2f((unsigned short)(a2 >> 16));
        float d  = half_sum_sel(fmaf(a1, hd1, a0 * hd0), hi);
        acc0 = fmaf(d, a0, acc0);
        acc1 = fmaf(d, a1, acc1);
    }
    if (j < end) {                          // odd final edge: only low half adds
        int s = srcs[j];
        uint32 a2 = *(const uint32*)(hpb + (size_t)s * OUT_F + half * 2);
        float a0 = bf2f((unsigned short)(a2 & 0xffff));
        float a1 = bf2f((unsigned short)(a2 >> 16));
        float d  = half_sum_sel(fmaf(a1, hd1, a0 * hd0), false);
        if (!hi) {
            acc0 = fmaf(d, a0, acc0);
            acc1 = fmaf(d, a1, acc1);
        }
    }

    acc0 += __shfl_xor(acc0, 32, 64);
    acc1 += __shfl_xor(acc1, 32, 64);

    if (!hi) {
        float r0, r1;
        if (end > beg) { r0 = acc0 * c; r1 = acc1 * c; }
        else           { r0 = hd0;      r1 = hd1;      }
        *(float2*)(out + (size_t)v * OUT_F + half * 2) = make_float2(r0, r1);
    }
}

extern "C" void kernel_launch(void* const* d_in, const int* in_sizes, int n_in,
                              void* d_out, int out_size, void* d_ws, size_t ws_size,
                              hipStream_t stream) {
    const float* h    = (const float*)d_in[0];
    const float* w    = (const float*)d_in[1];
    const float* attw = (const float*)d_in[2];
    const int*   src  = (const int*)d_in[3];
    const int*   dst  = (const int*)d_in[4];

    int N = in_sizes[0] / IN_F;
    int E = in_sizes[3];
    int NB = (N + 63) >> 6;    // 782 for N=50000 (NB <= NBKT_MAX)
    int ngemm = (N + 63) / 64;

    float* out = (float*)d_out;

    char* p = (char*)d_ws;
    unsigned short* hpb = (unsigned short*)p;  p += (size_t)N * OUT_F * sizeof(unsigned short);
    int* bkt_cnt    = (int*)p;                 p += (NBKT_MAX + 1) * sizeof(int);
    int* bkt_cursor = (int*)p;                 p += (NBKT_MAX + 1) * sizeof(int);
    int* bkt_base   = (int*)p;                 p += (NBKT_MAX + 1) * sizeof(int);
    int* row_ptr    = (int*)p;                 p += ((size_t)N + 8) * sizeof(int);
    uint32* pairs   = (uint32*)p;              p += (size_t)E * sizeof(uint32);
    int* srcs       = (int*)p;

    // zero bkt_cnt + bkt_cursor in one shot (contiguous)
    hipMemsetAsync(bkt_cnt, 0, 2 * (NBKT_MAX + 1) * sizeof(int), stream);

    gemm_hist_kernel<<<ngemm + HIST_BLOCKS, 256, 0, stream>>>(h, w, hpb, N,
                                                              dst, bkt_cnt, E, NB, ngemm);

    partition_kernel<<<PART_BLOCKS, 256, 0, stream>>>(src, dst, bkt_cnt, bkt_cursor,
                                                      bkt_base, pairs, E, NB);

    sortlocal_kernel<<<NB, 256, 0, stream>>>(pairs, bkt_base, srcs, row_ptr, N, E);

    accum_kernel<<<((size_t)N * 64 + 255) / 256, 256, 0, stream>>>(hpb, row_ptr, srcs, attw, out, N);
}

// Round 11
// 172.510 us; speedup vs baseline: 1.3633x; 1.1458x over previous
//
#include <hip/hip_runtime.h>

#define IN_F 256
#define OUT_F 64
#define NBKT_MAX 1024          // buckets of 64 dst nodes; supports N <= 65536
#define PART_BLOCKS 128
#define HIST_BLOCKS 256

typedef __attribute__((ext_vector_type(8))) short short8;
typedef __attribute__((ext_vector_type(4))) float f32x4;
typedef unsigned int uint32;

#define AS_I(f) __builtin_bit_cast(int, f)
#define AS_F(i) __builtin_bit_cast(float, i)
#define DPP_ADD(v, ctrl, rmask) \
    v += AS_F(__builtin_amdgcn_update_dpp(0, AS_I(v), ctrl, rmask, 0xf, true))

// Per-half (32-lane) sum: row_shr 1/2/4/8 + row_bcast:15 -> lane31 = low-half
// sum, lane63 = high-half sum. Select by half. Pure VALU pipe (DPP).
__device__ __forceinline__ float half_sum_sel(float p, bool hi) {
    DPP_ADD(p, 0x111, 0xf);
    DPP_ADD(p, 0x112, 0xf);
    DPP_ADD(p, 0x114, 0xf);
    DPP_ADD(p, 0x118, 0xf);
    DPP_ADD(p, 0x142, 0xa);
    float dlo = AS_F(__builtin_amdgcn_readlane(AS_I(p), 31));
    float dhi = AS_F(__builtin_amdgcn_readlane(AS_I(p), 63));
    return hi ? dhi : dlo;
}

__device__ __forceinline__ unsigned short f2bf(float f) {  // RNE f32->bf16
    uint32 u = __builtin_bit_cast(uint32, f);
    u += 0x7fffu + ((u >> 16) & 1u);
    return (unsigned short)(u >> 16);
}
__device__ __forceinline__ float bf2f(unsigned short s) {
    return __builtin_bit_cast(float, (uint32)s << 16);
}

// ---------------------------------------------------------------------------
// FUSED: blocks [0,ngemm) = MFMA gemm (w staged as bf16 B-frags in LDS);
// blocks [ngemm, ngemm+HIST_BLOCKS) = LDS-staged bucket histogram.
// ---------------------------------------------------------------------------
__global__ __launch_bounds__(256) void gemm_hist_kernel(const float* __restrict__ h,
                                                        const float* __restrict__ w,
                                                        unsigned short* __restrict__ hpb,
                                                        int N,
                                                        const int* __restrict__ dst,
                                                        int* __restrict__ bkt_cnt,
                                                        int E, int NB, int ngemm) {
    __shared__ char smem[32768];          // union: wfrag (gemm) / lcnt (hist)
    int b = blockIdx.x, t = threadIdx.x;

    if (b >= ngemm) {
        int* lcnt = (int*)smem;
        int hb = b - ngemm;
        for (int i = t; i < NB; i += 256) lcnt[i] = 0;
        __syncthreads();
        for (int e = hb * 256 + t; e < E; e += HIST_BLOCKS * 256)
            atomicAdd(&lcnt[dst[e] >> 6], 1);
        __syncthreads();
        for (int i = t; i < NB; i += 256)
            if (lcnt[i]) atomicAdd(&bkt_cnt[i], lcnt[i]);
        return;
    }

    short8* wfrag = (short8*)smem;        // 2048 slots * 16B = 32 KB
    for (int slot = t; slot < 2048; slot += 256) {
        int kb = slot >> 6, n = slot & 63;
        short8 v;
#pragma unroll
        for (int jj = 0; jj < 8; ++jj)
            v[jj] = (short)f2bf(w[(size_t)(kb * 8 + jj) * OUT_F + n]);
        wfrag[slot] = v;
    }
    __syncthreads();

    int wave = t >> 6, lane = t & 63;
    int n16  = lane & 15, quad = lane >> 4;
    int base = b * 64 + wave * 16;
    int arow_i = base + n16; if (arow_i >= N) arow_i = N - 1;
    const float* arow = h + (size_t)arow_i * IN_F;

    f32x4 acc[4];
#pragma unroll
    for (int ct = 0; ct < 4; ++ct) acc[ct] = (f32x4){0.f, 0.f, 0.f, 0.f};

#pragma unroll
    for (int ks = 0; ks < 8; ++ks) {
        int k0 = ks * 32;
        float4 a0 = *(const float4*)(arow + k0 + quad * 8);
        float4 a1 = *(const float4*)(arow + k0 + quad * 8 + 4);
        short8 af;
        af[0] = (short)f2bf(a0.x); af[1] = (short)f2bf(a0.y);
        af[2] = (short)f2bf(a0.z); af[3] = (short)f2bf(a0.w);
        af[4] = (short)f2bf(a1.x); af[5] = (short)f2bf(a1.y);
        af[6] = (short)f2bf(a1.z); af[7] = (short)f2bf(a1.w);
        int kb = ks * 4 + quad;
#pragma unroll
        for (int ct = 0; ct < 4; ++ct) {
            short8 bf = wfrag[kb * 64 + ct * 16 + n16];
            acc[ct] = __builtin_amdgcn_mfma_f32_16x16x32_bf16(af, bf, acc[ct], 0, 0, 0);
        }
    }

#pragma unroll
    for (int ct = 0; ct < 4; ++ct) {
#pragma unroll
        for (int r = 0; r < 4; ++r) {
            int ro = base + quad * 4 + r;
            if (ro < N) hpb[(size_t)ro * OUT_F + ct * 16 + n16] = f2bf(acc[ct][r]);
        }
    }
}

// ---------------------------------------------------------------------------
// Partition (128 blocks): A) each block redundantly scans bkt_cnt -> LDS
// sbase (block 0 also publishes global bkt_base); B) LDS-count own chunk ->
// ONE cursor atomic per (block,bucket) -> contiguous runs of packed pairs.
// ---------------------------------------------------------------------------
__global__ __launch_bounds__(256) void partition_kernel(const int* __restrict__ src,
                                                        const int* __restrict__ dst,
                                                        const int* __restrict__ bkt_cnt,
                                                        int* __restrict__ bkt_cursor,
                                                        int* __restrict__ bkt_base,
                                                        uint32* __restrict__ pairs,
                                                        int E, int NB) {
    __shared__ int sbase[NBKT_MAX + 1];
    __shared__ int lcnt[NBKT_MAX];
    __shared__ int gbase[NBKT_MAX];
    __shared__ int wsum2[4];

    int t = threadIdx.x, lane = t & 63, wid = t >> 6;

    // ---- Phase A: redundant exclusive scan of bkt_cnt (4 values/thread) ----
    int loc[4];
    int s = 0;
#pragma unroll
    for (int j = 0; j < 4; ++j) {
        int idx = t * 4 + j;
        int x = (idx < NB) ? bkt_cnt[idx] : 0;
        loc[j] = s; s += x;
    }
    int xs = s;
#pragma unroll
    for (int off = 1; off < 64; off <<= 1) {
        int y = __shfl_up(xs, off, 64);
        if (lane >= off) xs += y;
    }
    if (lane == 63) wsum2[wid] = xs;
    __syncthreads();
    int base_w = 0;
    for (int k = 0; k < wid; ++k) base_w += wsum2[k];
    int toff = base_w + xs - s;
#pragma unroll
    for (int j = 0; j < 4; ++j) {
        int idx = t * 4 + j;
        if (idx < NB) sbase[idx] = toff + loc[j];
    }
    if (t == 0) sbase[NB] = E;
    __syncthreads();

    if (blockIdx.x == 0) {
        for (int i = t; i <= NB; i += 256) bkt_base[i] = sbase[i];
    }

    // ---- Phase B: partition own chunk ----
    int chunk = (E + PART_BLOCKS - 1) / PART_BLOCKS;
    int s0 = blockIdx.x * chunk;
    int s1 = min(E, s0 + chunk);

    for (int i = t; i < NB; i += 256) lcnt[i] = 0;
    __syncthreads();
    for (int e = s0 + t; e < s1; e += 256)
        atomicAdd(&lcnt[dst[e] >> 6], 1);
    __syncthreads();
    for (int i = t; i < NB; i += 256) {
        int c = lcnt[i];
        if (c) gbase[i] = sbase[i] + atomicAdd(&bkt_cursor[i], c);
        lcnt[i] = 0;
    }
    __syncthreads();
    for (int e = s0 + t; e < s1; e += 256) {
        int d  = dst[e];
        int bk = d >> 6;
        int idx = atomicAdd(&lcnt[bk], 1);
        pairs[gbase[bk] + idx] = (uint32)src[e] | ((uint32)(d & 63) << 26);
    }
}

// ---------------------------------------------------------------------------
// Per-bucket LDS counting sort: bucket-sorted pairs -> node-sorted srcs +
// node-level row_ptr. Writes stay in the block's own ~4KB region (L2-hot).
// ---------------------------------------------------------------------------
__global__ __launch_bounds__(256) void sortlocal_kernel(const uint32* __restrict__ pairs,
                                                        const int* __restrict__ bkt_base,
                                                        int* __restrict__ srcs,
                                                        int* __restrict__ row_ptr,
                                                        int N, int E) {
    __shared__ int bin[64], excl[65], cur[64];
    int b = blockIdx.x, t = threadIdx.x;
    int beg = bkt_base[b], end = bkt_base[b + 1];

    if (t < 64) bin[t] = 0;
    __syncthreads();
    for (int i = beg + t; i < end; i += 256)
        atomicAdd(&bin[pairs[i] >> 26], 1);
    __syncthreads();
    if (t < 64) {
        int v = bin[t], x = v;
#pragma unroll
        for (int off = 1; off < 64; off <<= 1) {
            int y = __shfl_up(x, off, 64);
            if (t >= off) x += y;
        }
        excl[t] = x - v;
        cur[t]  = x - v;
        if (t == 63) excl[64] = x;
    }
    __syncthreads();
    if (t < 65) {
        int idx = b * 64 + t;
        if (idx <= N) row_ptr[idx] = beg + excl[t];
    }
    for (int i = beg + t; i < end; i += 256) {
        uint32 p = pairs[i];
        int dl   = (int)(p >> 26);
        int pos  = atomicAdd(&cur[dl], 1);
        srcs[beg + pos] = (int)(p & 0x3FFFFFFu);
    }
}

// ---------------------------------------------------------------------------
// Accumulate: one wave per dst node; lanes 0-31 = even edge, 32-63 = odd edge,
// lane carries 2 bf16 features -> one dword gather serves two edge rows.
// Main loop: 16 gathers = 32 edges MLP, ALL STATE IN NAMED SCALARS (no
// private arrays -> nothing for AMDGPUPromoteAlloca to push into LDS; R10's
// s4[8]/a2[16] arrays got LDS-promoted: 9M bank-conflict cycles).
// ---------------------------------------------------------------------------
#define GATH(S) (*(const uint32*)(hpb + (size_t)(S) * OUT_F + half * 2))
#define PROC(Q) { float a0 = bf2f((unsigned short)((Q) & 0xffff));            \
                  float a1 = bf2f((unsigned short)((Q) >> 16));               \
                  float dd = half_sum_sel(fmaf(a1, hd1, a0 * hd0), hi);       \
                  acc0 = fmaf(dd, a0, acc0); acc1 = fmaf(dd, a1, acc1); }

__global__ __launch_bounds__(256) void accum_kernel(const unsigned short* __restrict__ hpb,
                                                    const int* __restrict__ row_ptr,
                                                    const int* __restrict__ srcs,
                                                    const float* __restrict__ attw,
                                                    float* __restrict__ out, int N) {
    int v    = (blockIdx.x * blockDim.x + threadIdx.x) >> 6;
    int lane = threadIdx.x & 63;
    if (v >= N) return;

    int  half = lane & 31;
    bool hi   = lane >= 32;

    int beg = row_ptr[v];
    int end = row_ptr[v + 1];

    uint32 hd2 = *(const uint32*)(hpb + (size_t)v * OUT_F + half * 2);
    float hd0 = bf2f((unsigned short)(hd2 & 0xffff));
    float hd1 = bf2f((unsigned short)(hd2 >> 16));

    float c = 0.f;
#pragma unroll
    for (int i = 0; i < 8; ++i) c += attw[i];

    float acc0 = 0.f, acc1 = 0.f;
    int j = beg;

    for (; j + 32 <= end; j += 32) {   // 16 dword gathers in flight = 32 edges
        const int4* sp = (const int4*)(srcs + j);
        int4 sa = sp[0], sb = sp[1], sc = sp[2], sd = sp[3];
        int4 se = sp[4], sf = sp[5], sg = sp[6], sh = sp[7];
        uint32 q0  = GATH(hi ? sa.y : sa.x), q1  = GATH(hi ? sa.w : sa.z);
        uint32 q2  = GATH(hi ? sb.y : sb.x), q3  = GATH(hi ? sb.w : sb.z);
        uint32 q4  = GATH(hi ? sc.y : sc.x), q5  = GATH(hi ? sc.w : sc.z);
        uint32 q6  = GATH(hi ? sd.y : sd.x), q7  = GATH(hi ? sd.w : sd.z);
        uint32 q8  = GATH(hi ? se.y : se.x), q9  = GATH(hi ? se.w : se.z);
        uint32 q10 = GATH(hi ? sf.y : sf.x), q11 = GATH(hi ? sf.w : sf.z);
        uint32 q12 = GATH(hi ? sg.y : sg.x), q13 = GATH(hi ? sg.w : sg.z);
        uint32 q14 = GATH(hi ? sh.y : sh.x), q15 = GATH(hi ? sh.w : sh.z);
        PROC(q0)  PROC(q1)  PROC(q2)  PROC(q3)
        PROC(q4)  PROC(q5)  PROC(q6)  PROC(q7)
        PROC(q8)  PROC(q9)  PROC(q10) PROC(q11)
        PROC(q12) PROC(q13) PROC(q14) PROC(q15)
    }
    for (; j + 8 <= end; j += 8) {     // 4 gathers = 8 edges
        const int4* sp = (const int4*)(srcs + j);
        int4 sa = sp[0], sb = sp[1];
        uint32 q0 = GATH(hi ? sa.y : sa.x), q1 = GATH(hi ? sa.w : sa.z);
        uint32 q2 = GATH(hi ? sb.y : sb.x), q3 = GATH(hi ? sb.w : sb.z);
        PROC(q0) PROC(q1) PROC(q2) PROC(q3)
    }
    for (; j + 2 <= end; j += 2) {     // leftover pairs
        int s_lo = srcs[j], s_hi = srcs[j + 1];
        uint32 q = GATH(hi ? s_hi : s_lo);
        PROC(q)
    }
    if (j < end) {                     // odd final edge: only low half adds
        uint32 q = GATH(srcs[j]);
        float a0 = bf2f((unsigned short)(q & 0xffff));
        float a1 = bf2f((unsigned short)(q >> 16));
        float dd = half_sum_sel(fmaf(a1, hd1, a0 * hd0), false);
        if (!hi) {
            acc0 = fmaf(dd, a0, acc0);
            acc1 = fmaf(dd, a1, acc1);
        }
    }

    acc0 += __shfl_xor(acc0, 32, 64);
    acc1 += __shfl_xor(acc1, 32, 64);

    if (!hi) {
        float r0, r1;
        if (end > beg) { r0 = acc0 * c; r1 = acc1 * c; }
        else           { r0 = hd0;      r1 = hd1;      }
        *(float2*)(out + (size_t)v * OUT_F + half * 2) = make_float2(r0, r1);
    }
}

extern "C" void kernel_launch(void* const* d_in, const int* in_sizes, int n_in,
                              void* d_out, int out_size, void* d_ws, size_t ws_size,
                              hipStream_t stream) {
    const float* h    = (const float*)d_in[0];
    const float* w    = (const float*)d_in[1];
    const float* attw = (const float*)d_in[2];
    const int*   src  = (const int*)d_in[3];
    const int*   dst  = (const int*)d_in[4];

    int N = in_sizes[0] / IN_F;
    int E = in_sizes[3];
    int NB = (N + 63) >> 6;    // 782 for N=50000 (NB <= NBKT_MAX)
    int ngemm = (N + 63) / 64;

    float* out = (float*)d_out;

    char* p = (char*)d_ws;
    unsigned short* hpb = (unsigned short*)p;  p += (size_t)N * OUT_F * sizeof(unsigned short);
    int* bkt_cnt    = (int*)p;                 p += (NBKT_MAX + 1) * sizeof(int);
    int* bkt_cursor = (int*)p;                 p += (NBKT_MAX + 1) * sizeof(int);
    int* bkt_base   = (int*)p;                 p += (NBKT_MAX + 1) * sizeof(int);
    int* row_ptr    = (int*)p;                 p += ((size_t)N + 8) * sizeof(int);
    uint32* pairs   = (uint32*)p;              p += (size_t)E * sizeof(uint32);
    int* srcs       = (int*)p;

    // zero bkt_cnt + bkt_cursor in one shot (contiguous)
    hipMemsetAsync(bkt_cnt, 0, 2 * (NBKT_MAX + 1) * sizeof(int), stream);

    gemm_hist_kernel<<<ngemm + HIST_BLOCKS, 256, 0, stream>>>(h, w, hpb, N,
                                                              dst, bkt_cnt, E, NB, ngemm);

    partition_kernel<<<PART_BLOCKS, 256, 0, stream>>>(src, dst, bkt_cnt, bkt_cursor,
                                                      bkt_base, pairs, E, NB);

    sortlocal_kernel<<<NB, 256, 0, stream>>>(pairs, bkt_base, srcs, row_ptr, N, E);

    accum_kernel<<<((size_t)N * 64 + 255) / 256, 256, 0, stream>>>(hpb, row_ptr, srcs, attw, out, N);
}

// Round 12
// 154.797 us; speedup vs baseline: 1.5193x; 1.1144x over previous
//
#include <hip/hip_runtime.h>

#define IN_F 256
#define OUT_F 64
#define NBKT_MAX 1024          // buckets of 64 dst nodes; supports N <= 65536
#define PART_BLOCKS 128
#define HIST_BLOCKS 256
#define CAP 3072               // LDS edge capacity per bucket (mean ~1024, max ~1150)

typedef __attribute__((ext_vector_type(8))) short short8;
typedef __attribute__((ext_vector_type(4))) float f32x4;
typedef unsigned int uint32;

#define AS_I(f) __builtin_bit_cast(int, f)
#define AS_F(i) __builtin_bit_cast(float, i)
#define DPP_ADD(v, ctrl, rmask) \
    v += AS_F(__builtin_amdgcn_update_dpp(0, AS_I(v), ctrl, rmask, 0xf, true))

// Per-half (32-lane) sum: row_shr 1/2/4/8 + row_bcast:15 -> lane31 = low-half
// sum, lane63 = high-half sum. Select by half. Pure VALU pipe (DPP).
__device__ __forceinline__ float half_sum_sel(float p, bool hi) {
    DPP_ADD(p, 0x111, 0xf);
    DPP_ADD(p, 0x112, 0xf);
    DPP_ADD(p, 0x114, 0xf);
    DPP_ADD(p, 0x118, 0xf);
    DPP_ADD(p, 0x142, 0xa);
    float dlo = AS_F(__builtin_amdgcn_readlane(AS_I(p), 31));
    float dhi = AS_F(__builtin_amdgcn_readlane(AS_I(p), 63));
    return hi ? dhi : dlo;
}

__device__ __forceinline__ unsigned short f2bf(float f) {  // RNE f32->bf16
    uint32 u = __builtin_bit_cast(uint32, f);
    u += 0x7fffu + ((u >> 16) & 1u);
    return (unsigned short)(u >> 16);
}
__device__ __forceinline__ float bf2f(unsigned short s) {
    return __builtin_bit_cast(float, (uint32)s << 16);
}

// ---------------------------------------------------------------------------
// FUSED: blocks [0,ngemm) = MFMA gemm (w staged as bf16 B-frags in LDS);
// blocks [ngemm, ngemm+HIST_BLOCKS) = LDS-staged bucket histogram.
// ---------------------------------------------------------------------------
__global__ __launch_bounds__(256) void gemm_hist_kernel(const float* __restrict__ h,
                                                        const float* __restrict__ w,
                                                        unsigned short* __restrict__ hpb,
                                                        int N,
                                                        const int* __restrict__ dst,
                                                        int* __restrict__ bkt_cnt,
                                                        int E, int NB, int ngemm) {
    __shared__ char smem[32768];          // union: wfrag (gemm) / lcnt (hist)
    int b = blockIdx.x, t = threadIdx.x;

    if (b >= ngemm) {
        int* lcnt = (int*)smem;
        int hb = b - ngemm;
        for (int i = t; i < NB; i += 256) lcnt[i] = 0;
        __syncthreads();
        for (int e = hb * 256 + t; e < E; e += HIST_BLOCKS * 256)
            atomicAdd(&lcnt[dst[e] >> 6], 1);
        __syncthreads();
        for (int i = t; i < NB; i += 256)
            if (lcnt[i]) atomicAdd(&bkt_cnt[i], lcnt[i]);
        return;
    }

    short8* wfrag = (short8*)smem;        // 2048 slots * 16B = 32 KB
    for (int slot = t; slot < 2048; slot += 256) {
        int kb = slot >> 6, n = slot & 63;
        short8 v;
#pragma unroll
        for (int jj = 0; jj < 8; ++jj)
            v[jj] = (short)f2bf(w[(size_t)(kb * 8 + jj) * OUT_F + n]);
        wfrag[slot] = v;
    }
    __syncthreads();

    int wave = t >> 6, lane = t & 63;
    int n16  = lane & 15, quad = lane >> 4;
    int base = b * 64 + wave * 16;
    int arow_i = base + n16; if (arow_i >= N) arow_i = N - 1;
    const float* arow = h + (size_t)arow_i * IN_F;

    f32x4 acc[4];
#pragma unroll
    for (int ct = 0; ct < 4; ++ct) acc[ct] = (f32x4){0.f, 0.f, 0.f, 0.f};

#pragma unroll
    for (int ks = 0; ks < 8; ++ks) {
        int k0 = ks * 32;
        float4 a0 = *(const float4*)(arow + k0 + quad * 8);
        float4 a1 = *(const float4*)(arow + k0 + quad * 8 + 4);
        short8 af;
        af[0] = (short)f2bf(a0.x); af[1] = (short)f2bf(a0.y);
        af[2] = (short)f2bf(a0.z); af[3] = (short)f2bf(a0.w);
        af[4] = (short)f2bf(a1.x); af[5] = (short)f2bf(a1.y);
        af[6] = (short)f2bf(a1.z); af[7] = (short)f2bf(a1.w);
        int kb = ks * 4 + quad;
#pragma unroll
        for (int ct = 0; ct < 4; ++ct) {
            short8 bf = wfrag[kb * 64 + ct * 16 + n16];
            acc[ct] = __builtin_amdgcn_mfma_f32_16x16x32_bf16(af, bf, acc[ct], 0, 0, 0);
        }
    }

#pragma unroll
    for (int ct = 0; ct < 4; ++ct) {
#pragma unroll
        for (int r = 0; r < 4; ++r) {
            int ro = base + quad * 4 + r;
            if (ro < N) hpb[(size_t)ro * OUT_F + ct * 16 + n16] = f2bf(acc[ct][r]);
        }
    }
}

// ---------------------------------------------------------------------------
// Partition (128 blocks x 512 thr): A) each block redundantly scans bkt_cnt
// -> LDS sbase (block 0 publishes global bkt_base); B) LDS-count own chunk ->
// ONE cursor atomic per (block,bucket) -> contiguous ~8-edge runs of packed
// (dstLocal<<26 | src) words.
// ---------------------------------------------------------------------------
__global__ __launch_bounds__(512) void partition_kernel(const int* __restrict__ src,
                                                        const int* __restrict__ dst,
                                                        const int* __restrict__ bkt_cnt,
                                                        int* __restrict__ bkt_cursor,
                                                        int* __restrict__ bkt_base,
                                                        uint32* __restrict__ pairs,
                                                        int E, int NB) {
    __shared__ int sbase[NBKT_MAX + 1];
    __shared__ int lcnt[NBKT_MAX];
    __shared__ int gbase[NBKT_MAX];
    __shared__ int wsum2[8];

    int t = threadIdx.x, lane = t & 63, wid = t >> 6;

    // ---- Phase A: redundant exclusive scan of bkt_cnt (2 values/thread) ----
    int loc0, loc1;
    int x0 = (t * 2     < NB) ? bkt_cnt[t * 2]     : 0;
    int x1 = (t * 2 + 1 < NB) ? bkt_cnt[t * 2 + 1] : 0;
    loc0 = 0; loc1 = x0;
    int s = x0 + x1;
    int xs = s;
#pragma unroll
    for (int off = 1; off < 64; off <<= 1) {
        int y = __shfl_up(xs, off, 64);
        if (lane >= off) xs += y;
    }
    if (lane == 63) wsum2[wid] = xs;
    __syncthreads();
    int base_w = 0;
    for (int k = 0; k < wid; ++k) base_w += wsum2[k];
    int toff = base_w + xs - s;
    if (t * 2     < NB) sbase[t * 2]     = toff + loc0;
    if (t * 2 + 1 < NB) sbase[t * 2 + 1] = toff + loc1;
    if (t == 0) sbase[NB] = E;
    __syncthreads();

    if (blockIdx.x == 0) {
        for (int i = t; i <= NB; i += 512) bkt_base[i] = sbase[i];
    }

    // ---- Phase B: partition own chunk ----
    int chunk = (E + PART_BLOCKS - 1) / PART_BLOCKS;
    int s0 = blockIdx.x * chunk;
    int s1 = min(E, s0 + chunk);

    for (int i = t; i < NB; i += 512) lcnt[i] = 0;
    __syncthreads();
    for (int e = s0 + t; e < s1; e += 512)
        atomicAdd(&lcnt[dst[e] >> 6], 1);
    __syncthreads();
    for (int i = t; i < NB; i += 512) {
        int c = lcnt[i];
        if (c) gbase[i] = sbase[i] + atomicAdd(&bkt_cursor[i], c);
        lcnt[i] = 0;
    }
    __syncthreads();
    for (int e = s0 + t; e < s1; e += 512) {
        int d  = dst[e];
        int bk = d >> 6;
        int idx = atomicAdd(&lcnt[bk], 1);
        pairs[gbase[bk] + idx] = (uint32)src[e] | ((uint32)(d & 63) << 26);
    }
}

// ---------------------------------------------------------------------------
// FUSED sort+accumulate: block = bucket of 64 dst nodes, 512 thr (8 waves).
// 1) counting-sort the bucket's pairs into LDS slds (node-sorted edge srcs);
// 2) each wave accumulates 8 nodes: lanes 0-31 = even edge, 32-63 = odd edge,
//    lane carries 2 bf16 features -> one dword gather serves two edge rows;
//    16-edge/8-gather batches, ALL SCALAR STATE (no alloca->LDS promotion).
// Fallback for nE > CAP: direct filtered scan of global pairs (never taken
// for uniform dst; correctness-only).
// ---------------------------------------------------------------------------
#define GATH(S) (*(const uint32*)(hpb + (size_t)(S) * OUT_F + half * 2))
#define PROC(Q) { float a0 = bf2f((unsigned short)((Q) & 0xffff));            \
                  float a1 = bf2f((unsigned short)((Q) >> 16));               \
                  float dd = half_sum_sel(fmaf(a1, hd1, a0 * hd0), hi);       \
                  acc0 = fmaf(dd, a0, acc0); acc1 = fmaf(dd, a1, acc1); }

__global__ __launch_bounds__(512) void accum_sort_kernel(const unsigned short* __restrict__ hpb,
                                                         const uint32* __restrict__ pairs,
                                                         const int* __restrict__ bkt_base,
                                                         const float* __restrict__ attw,
                                                         float* __restrict__ out, int N) {
    __shared__ int slds[CAP];
    __shared__ int bin[64], excl[65], cur[64];

    int b = blockIdx.x, t = threadIdx.x;
    int wid = t >> 6, lane = t & 63;
    int half = lane & 31;
    bool hi  = lane >= 32;
    int node0 = b * 64;

    int beg = bkt_base[b], end = bkt_base[b + 1];
    int nE  = end - beg;

    float c = 0.f;
#pragma unroll
    for (int i = 0; i < 8; ++i) c += attw[i];

    if (nE <= CAP) {
        // ---- counting sort into LDS ----
        if (t < 64) bin[t] = 0;
        __syncthreads();
        for (int i = beg + t; i < end; i += 512)
            atomicAdd(&bin[pairs[i] >> 26], 1);
        __syncthreads();
        if (t < 64) {
            int v = bin[t], x = v;
#pragma unroll
            for (int off = 1; off < 64; off <<= 1) {
                int y = __shfl_up(x, off, 64);
                if (t >= off) x += y;
            }
            excl[t] = x - v;
            cur[t]  = x - v;
            if (t == 63) excl[64] = x;
        }
        __syncthreads();
        for (int i = beg + t; i < end; i += 512) {
            uint32 p = pairs[i];
            int dl   = (int)(p >> 26);
            int pos  = atomicAdd(&cur[dl], 1);
            slds[pos] = (int)(p & 0x3FFFFFFu);
        }
        __syncthreads();

        // ---- accumulate: wave wid handles nodes wid + 8k, k = 0..7 ----
#pragma unroll 1
        for (int k = 0; k < 8; ++k) {
            int n    = wid + 8 * k;
            int node = node0 + n;
            if (node >= N) continue;

            int jb = excl[n], je = excl[n + 1];

            uint32 hd2 = *(const uint32*)(hpb + (size_t)node * OUT_F + half * 2);
            float hd0 = bf2f((unsigned short)(hd2 & 0xffff));
            float hd1 = bf2f((unsigned short)(hd2 >> 16));

            float acc0 = 0.f, acc1 = 0.f;
            int j = jb;
            int sel = hi ? 1 : 0;

            for (; j + 16 <= je; j += 16) {      // 8 gathers = 16 edges in flight
                int i0 = slds[j + 0  + sel], i1 = slds[j + 2  + sel];
                int i2 = slds[j + 4  + sel], i3 = slds[j + 6  + sel];
                int i4 = slds[j + 8  + sel], i5 = slds[j + 10 + sel];
                int i6 = slds[j + 12 + sel], i7 = slds[j + 14 + sel];
                uint32 q0 = GATH(i0), q1 = GATH(i1), q2 = GATH(i2), q3 = GATH(i3);
                uint32 q4 = GATH(i4), q5 = GATH(i5), q6 = GATH(i6), q7 = GATH(i7);
                PROC(q0) PROC(q1) PROC(q2) PROC(q3)
                PROC(q4) PROC(q5) PROC(q6) PROC(q7)
            }
            for (; j + 8 <= je; j += 8) {        // 4 gathers = 8 edges
                int i0 = slds[j + 0 + sel], i1 = slds[j + 2 + sel];
                int i2 = slds[j + 4 + sel], i3 = slds[j + 6 + sel];
                uint32 q0 = GATH(i0), q1 = GATH(i1), q2 = GATH(i2), q3 = GATH(i3);
                PROC(q0) PROC(q1) PROC(q2) PROC(q3)
            }
            for (; j + 2 <= je; j += 2) {
                int i0 = slds[j + sel];
                uint32 q0 = GATH(i0);
                PROC(q0)
            }
            if (j < je) {                        // odd final edge: low half only
                int i0 = slds[j];
                uint32 q0 = GATH(i0);
                float a0 = bf2f((unsigned short)(q0 & 0xffff));
                float a1 = bf2f((unsigned short)(q0 >> 16));
                float dd = half_sum_sel(fmaf(a1, hd1, a0 * hd0), false);
                if (!hi) {
                    acc0 = fmaf(dd, a0, acc0);
                    acc1 = fmaf(dd, a1, acc1);
                }
            }

            acc0 += __shfl_xor(acc0, 32, 64);
            acc1 += __shfl_xor(acc1, 32, 64);

            if (!hi) {
                float r0, r1;
                if (je > jb) { r0 = acc0 * c; r1 = acc1 * c; }
                else         { r0 = hd0;      r1 = hd1;      }
                *(float2*)(out + (size_t)node * OUT_F + half * 2) = make_float2(r0, r1);
            }
        }
    } else {
        // ---- fallback (correctness only; not expected to trigger) ----
#pragma unroll 1
        for (int k = 0; k < 8; ++k) {
            int n    = wid + 8 * k;
            int node = node0 + n;
            if (node >= N) continue;

            uint32 hd2 = *(const uint32*)(hpb + (size_t)node * OUT_F + half * 2);
            float hd0 = bf2f((unsigned short)(hd2 & 0xffff));
            float hd1 = bf2f((unsigned short)(hd2 >> 16));

            float acc0 = 0.f, acc1 = 0.f;
            int deg = 0;
            for (int i = beg; i < end; ++i) {
                uint32 p = pairs[i];
                if ((int)(p >> 26) == n) {
                    ++deg;
                    uint32 q0 = GATH((int)(p & 0x3FFFFFFu));
                    float a0 = bf2f((unsigned short)(q0 & 0xffff));
                    float a1 = bf2f((unsigned short)(q0 >> 16));
                    float dd = half_sum_sel(fmaf(a1, hd1, a0 * hd0), false);
                    if (!hi) {
                        acc0 = fmaf(dd, a0, acc0);
                        acc1 = fmaf(dd, a1, acc1);
                    }
                }
            }
            acc0 += __shfl_xor(acc0, 32, 64);
            acc1 += __shfl_xor(acc1, 32, 64);
            if (!hi) {
                float r0, r1;
                if (deg > 0) { r0 = acc0 * c; r1 = acc1 * c; }
                else         { r0 = hd0;      r1 = hd1;      }
                *(float2*)(out + (size_t)node * OUT_F + half * 2) = make_float2(r0, r1);
            }
        }
    }
}

extern "C" void kernel_launch(void* const* d_in, const int* in_sizes, int n_in,
                              void* d_out, int out_size, void* d_ws, size_t ws_size,
                              hipStream_t stream) {
    const float* h    = (const float*)d_in[0];
    const float* w    = (const float*)d_in[1];
    const float* attw = (const float*)d_in[2];
    const int*   src  = (const int*)d_in[3];
    const int*   dst  = (const int*)d_in[4];

    int N = in_sizes[0] / IN_F;
    int E = in_sizes[3];
    int NB = (N + 63) >> 6;    // 782 for N=50000 (NB <= NBKT_MAX)
    int ngemm = (N + 63) / 64;

    float* out = (float*)d_out;

    char* p = (char*)d_ws;
    unsigned short* hpb = (unsigned short*)p;  p += (size_t)N * OUT_F * sizeof(unsigned short);
    int* bkt_cnt    = (int*)p;                 p += (NBKT_MAX + 1) * sizeof(int);
    int* bkt_cursor = (int*)p;                 p += (NBKT_MAX + 1) * sizeof(int);
    int* bkt_base   = (int*)p;                 p += (NBKT_MAX + 1) * sizeof(int);
    uint32* pairs   = (uint32*)p;

    // zero bkt_cnt + bkt_cursor in one shot (contiguous)
    hipMemsetAsync(bkt_cnt, 0, 2 * (NBKT_MAX + 1) * sizeof(int), stream);

    gemm_hist_kernel<<<ngemm + HIST_BLOCKS, 256, 0, stream>>>(h, w, hpb, N,
                                                              dst, bkt_cnt, E, NB, ngemm);

    partition_kernel<<<PART_BLOCKS, 512, 0, stream>>>(src, dst, bkt_cnt, bkt_cursor,
                                                      bkt_base, pairs, E, NB);

    accum_sort_kernel<<<NB, 512, 0, stream>>>(hpb, pairs, bkt_base, attw, out, N);
}

// Round 13
// 147.857 us; speedup vs baseline: 1.5906x; 1.0469x over previous
//
#include <hip/hip_runtime.h>

#define IN_F 256
#define OUT_F 64
#define NBKT_MAX 1024          // buckets of 64 dst nodes; supports N <= 65536
#define PART_BLOCKS 128
#define CAP 3072               // LDS edge capacity per bucket (mean ~1023, max ~1150)

typedef __attribute__((ext_vector_type(8))) short short8;
typedef __attribute__((ext_vector_type(4))) float f32x4;
typedef unsigned int uint32;

#define AS_I(f) __builtin_bit_cast(int, f)
#define AS_F(i) __builtin_bit_cast(float, i)
#define DPP_ADD(v, ctrl, rmask) \
    v += AS_F(__builtin_amdgcn_update_dpp(0, AS_I(v), ctrl, rmask, 0xf, true))

// Per-half (32-lane) sum: row_shr 1/2/4/8 + row_bcast:15 -> lane31 = low-half
// sum, lane63 = high-half sum. Select by half. Pure VALU pipe (DPP).
__device__ __forceinline__ float half_sum_sel(float p, bool hi) {
    DPP_ADD(p, 0x111, 0xf);
    DPP_ADD(p, 0x112, 0xf);
    DPP_ADD(p, 0x114, 0xf);
    DPP_ADD(p, 0x118, 0xf);
    DPP_ADD(p, 0x142, 0xa);
    float dlo = AS_F(__builtin_amdgcn_readlane(AS_I(p), 31));
    float dhi = AS_F(__builtin_amdgcn_readlane(AS_I(p), 63));
    return hi ? dhi : dlo;
}

__device__ __forceinline__ unsigned short f2bf(float f) {  // RNE f32->bf16
    uint32 u = __builtin_bit_cast(uint32, f);
    u += 0x7fffu + ((u >> 16) & 1u);
    return (unsigned short)(u >> 16);
}
__device__ __forceinline__ float bf2f(unsigned short s) {
    return __builtin_bit_cast(float, (uint32)s << 16);
}

// ---------------------------------------------------------------------------
// FUSED gemm + segment-table partition, 256 thr.
// Blocks [0, PART_BLOCKS): partition own edge chunk into bucket-grouped runs
//   inside the block's OWN region of pairs (dense; no cross-block atomics,
//   no pre-zeroed global state), and write the segment table row
//   tbl[p][b] = absolute start of p's bucket-b run (tbl[p][NB] = chunk end).
//   Placed FIRST in the grid so they dispatch before the gemm wave.
// Blocks [PART_BLOCKS, ...): MFMA gemm hpb = bf16(h @ w), w staged as bf16
//   B-fragments in LDS (verified R5-R12: absmax 4.0 vs threshold 19.44).
// ---------------------------------------------------------------------------
__global__ __launch_bounds__(256) void gemm_part_kernel(const float* __restrict__ h,
                                                        const float* __restrict__ w,
                                                        unsigned short* __restrict__ hpb,
                                                        int N,
                                                        const int* __restrict__ src,
                                                        const int* __restrict__ dst,
                                                        int* __restrict__ tbl,
                                                        uint32* __restrict__ pairs,
                                                        int E, int NB) {
    __shared__ char smem[32768];          // union: lcnt (partition) / wfrag (gemm)
    __shared__ int wsum[4];
    int b = blockIdx.x, t = threadIdx.x;

    if (b < PART_BLOCKS) {
        // ---- partition path ----
        int* lcnt = (int*)smem;           // NBKT_MAX ints: counts, then cursors
        int lane = t & 63, wid = t >> 6;
        int chunk = (E + PART_BLOCKS - 1) / PART_BLOCKS;
        int s0 = b * chunk, s1 = min(E, s0 + chunk);

        for (int i = t; i < NB; i += 256) lcnt[i] = 0;
        __syncthreads();
        for (int e = s0 + t; e < s1; e += 256)
            atomicAdd(&lcnt[dst[e] >> 6], 1);
        __syncthreads();

        // exclusive scan of lcnt (4 consecutive values/thread, scalar locals)
        int i0 = t * 4;
        int x0 = (i0     < NB) ? lcnt[i0]     : 0;
        int x1 = (i0 + 1 < NB) ? lcnt[i0 + 1] : 0;
        int x2 = (i0 + 2 < NB) ? lcnt[i0 + 2] : 0;
        int x3 = (i0 + 3 < NB) ? lcnt[i0 + 3] : 0;
        int l1 = x0, l2 = x0 + x1, l3 = x0 + x1 + x2;
        int s  = l3 + x3;
        int xs = s;
#pragma unroll
        for (int off = 1; off < 64; off <<= 1) {
            int y = __shfl_up(xs, off, 64);
            if (lane >= off) xs += y;
        }
        if (lane == 63) wsum[wid] = xs;
        __syncthreads();                  // all lcnt reads done before overwrite
        int basew = 0;
        for (int k = 0; k < wid; ++k) basew += wsum[k];
        int toff = basew + xs - s;

        int* trow = tbl + (size_t)b * (NB + 1);
        if (i0     < NB) { trow[i0]     = s0 + toff;      lcnt[i0]     = toff;      }
        if (i0 + 1 < NB) { trow[i0 + 1] = s0 + toff + l1; lcnt[i0 + 1] = toff + l1; }
        if (i0 + 2 < NB) { trow[i0 + 2] = s0 + toff + l2; lcnt[i0 + 2] = toff + l2; }
        if (i0 + 3 < NB) { trow[i0 + 3] = s0 + toff + l3; lcnt[i0 + 3] = toff + l3; }
        if (t == 0) trow[NB] = s1;
        __syncthreads();

        // place pass: lcnt is now the per-bucket cursor (chunk-relative)
        for (int e = s0 + t; e < s1; e += 256) {
            int d  = dst[e];
            int bk = d >> 6;
            int idx = atomicAdd(&lcnt[bk], 1);
            pairs[s0 + idx] = (uint32)src[e] | ((uint32)(d & 63) << 26);
        }
        return;
    }

    // ---- gemm path ----
    int gb = b - PART_BLOCKS;
    short8* wfrag = (short8*)smem;        // 2048 slots * 16B = 32 KB
    for (int slot = t; slot < 2048; slot += 256) {
        int kb = slot >> 6, n = slot & 63;
        short8 v;
#pragma unroll
        for (int jj = 0; jj < 8; ++jj)
            v[jj] = (short)f2bf(w[(size_t)(kb * 8 + jj) * OUT_F + n]);
        wfrag[slot] = v;
    }
    __syncthreads();

    int wave = t >> 6, lane = t & 63;
    int n16  = lane & 15, quad = lane >> 4;
    int base = gb * 64 + wave * 16;
    int arow_i = base + n16; if (arow_i >= N) arow_i = N - 1;
    const float* arow = h + (size_t)arow_i * IN_F;

    f32x4 acc[4];
#pragma unroll
    for (int ct = 0; ct < 4; ++ct) acc[ct] = (f32x4){0.f, 0.f, 0.f, 0.f};

#pragma unroll
    for (int ks = 0; ks < 8; ++ks) {
        int k0 = ks * 32;
        float4 a0 = *(const float4*)(arow + k0 + quad * 8);
        float4 a1 = *(const float4*)(arow + k0 + quad * 8 + 4);
        short8 af;
        af[0] = (short)f2bf(a0.x); af[1] = (short)f2bf(a0.y);
        af[2] = (short)f2bf(a0.z); af[3] = (short)f2bf(a0.w);
        af[4] = (short)f2bf(a1.x); af[5] = (short)f2bf(a1.y);
        af[6] = (short)f2bf(a1.z); af[7] = (short)f2bf(a1.w);
        int kb = ks * 4 + quad;
#pragma unroll
        for (int ct = 0; ct < 4; ++ct) {
            short8 bf = wfrag[kb * 64 + ct * 16 + n16];
            acc[ct] = __builtin_amdgcn_mfma_f32_16x16x32_bf16(af, bf, acc[ct], 0, 0, 0);
        }
    }

#pragma unroll
    for (int ct = 0; ct < 4; ++ct) {
#pragma unroll
        for (int r = 0; r < 4; ++r) {
            int ro = base + quad * 4 + r;
            if (ro < N) hpb[(size_t)ro * OUT_F + ct * 16 + n16] = f2bf(acc[ct][r]);
        }
    }
}

// ---------------------------------------------------------------------------
// FUSED gather+sort+accumulate: block = bucket of 64 dst nodes, 512 thr.
// 1) read 128 segment descriptors (tbl column), wave-scan lengths -> psum;
// 2) stage the bucket's edges from 128 pair-runs into LDS (binary search in
//    psum for segment); 3) LDS counting sort by dstLocal; 4) per-node wave
//    accumulate: lanes 0-31 = even edge, 32-63 = odd edge, lane = 2 bf16
//    features -> one dword gather serves two edge rows; 16-edge batches,
//    ALL SCALAR STATE (R10 lesson: private arrays get LDS-promoted).
// Fallback nE > CAP: filtered scan over segments (correctness only).
// ---------------------------------------------------------------------------
#define GATH(S) (*(const uint32*)(hpb + (size_t)(S) * OUT_F + half * 2))
#define PROC(Q) { float a0 = bf2f((unsigned short)((Q) & 0xffff));            \
                  float a1 = bf2f((unsigned short)((Q) >> 16));               \
                  float dd = half_sum_sel(fmaf(a1, hd1, a0 * hd0), hi);       \
                  acc0 = fmaf(dd, a0, acc0); acc1 = fmaf(dd, a1, acc1); }

__global__ __launch_bounds__(512) void accum_kernel(const unsigned short* __restrict__ hpb,
                                                    const uint32* __restrict__ pairs,
                                                    const int* __restrict__ tbl,
                                                    const float* __restrict__ attw,
                                                    float* __restrict__ out, int N, int NB) {
    __shared__ uint32 sraw[CAP];
    __shared__ int slds[CAP];
    __shared__ int segb[PART_BLOCKS], slen[PART_BLOCKS], psum[PART_BLOCKS + 1];
    __shared__ int bin[64], excl[65], cur[64];

    int b = blockIdx.x, t = threadIdx.x;
    int wid = t >> 6, lane = t & 63;
    int half = lane & 31;
    bool hi  = lane >= 32;
    int node0 = b * 64;

    // ---- segment descriptors ----
    if (t < PART_BLOCKS) {
        const int* trow = tbl + (size_t)t * (NB + 1);
        int b0 = trow[b];
        segb[t] = b0;
        slen[t] = trow[b + 1] - b0;
    }
    __syncthreads();
    if (wid == 0) {                       // wave-0 exclusive scan of 128 lengths
        int l0 = slen[lane * 2], l1 = slen[lane * 2 + 1];
        int s = l0 + l1, xs = s;
#pragma unroll
        for (int off = 1; off < 64; off <<= 1) {
            int y = __shfl_up(xs, off, 64);
            if (lane >= off) xs += y;
        }
        int ex = xs - s;
        psum[lane * 2]     = ex;
        psum[lane * 2 + 1] = ex + l0;
        if (lane == 63) psum[PART_BLOCKS] = xs;
    }
    __syncthreads();
    int nE = psum[PART_BLOCKS];

    float c = 0.f;
#pragma unroll
    for (int i = 0; i < 8; ++i) c += attw[i];

    if (nE <= CAP) {
        // ---- stage: binary search psum for segment of each edge ----
        for (int i = t; i < nE; i += 512) {
            int lo = 0, hh = PART_BLOCKS - 1;
#pragma unroll
            for (int it = 0; it < 7; ++it) {   // 2^7 = 128
                int mid = (lo + hh + 1) >> 1;
                if (psum[mid] <= i) lo = mid; else hh = mid - 1;
            }
            sraw[i] = pairs[segb[lo] + (i - psum[lo])];
        }
        // ---- counting sort in LDS ----
        if (t < 64) bin[t] = 0;
        __syncthreads();
        for (int i = t; i < nE; i += 512)
            atomicAdd(&bin[sraw[i] >> 26], 1);
        __syncthreads();
        if (t < 64) {
            int v = bin[t], x = v;
#pragma unroll
            for (int off = 1; off < 64; off <<= 1) {
                int y = __shfl_up(x, off, 64);
                if (t >= off) x += y;
            }
            excl[t] = x - v;
            cur[t]  = x - v;
            if (t == 63) excl[64] = x;
        }
        __syncthreads();
        for (int i = t; i < nE; i += 512) {
            uint32 p = sraw[i];
            int pos = atomicAdd(&cur[(int)(p >> 26)], 1);
            slds[pos] = (int)(p & 0x3FFFFFFu);
        }
        __syncthreads();

        // ---- accumulate: wave wid handles nodes wid + 8k ----
#pragma unroll 1
        for (int k = 0; k < 8; ++k) {
            int n    = wid + 8 * k;
            int node = node0 + n;
            if (node >= N) continue;

            int jb = excl[n], je = excl[n + 1];

            uint32 hd2 = *(const uint32*)(hpb + (size_t)node * OUT_F + half * 2);
            float hd0 = bf2f((unsigned short)(hd2 & 0xffff));
            float hd1 = bf2f((unsigned short)(hd2 >> 16));

            float acc0 = 0.f, acc1 = 0.f;
            int j = jb;
            int sel = hi ? 1 : 0;

            for (; j + 16 <= je; j += 16) {      // 8 gathers = 16 edges in flight
                int i0 = slds[j + 0  + sel], i1 = slds[j + 2  + sel];
                int i2 = slds[j + 4  + sel], i3 = slds[j + 6  + sel];
                int i4 = slds[j + 8  + sel], i5 = slds[j + 10 + sel];
                int i6 = slds[j + 12 + sel], i7 = slds[j + 14 + sel];
                uint32 q0 = GATH(i0), q1 = GATH(i1), q2 = GATH(i2), q3 = GATH(i3);
                uint32 q4 = GATH(i4), q5 = GATH(i5), q6 = GATH(i6), q7 = GATH(i7);
                PROC(q0) PROC(q1) PROC(q2) PROC(q3)
                PROC(q4) PROC(q5) PROC(q6) PROC(q7)
            }
            for (; j + 8 <= je; j += 8) {        // 4 gathers = 8 edges
                int i0 = slds[j + 0 + sel], i1 = slds[j + 2 + sel];
                int i2 = slds[j + 4 + sel], i3 = slds[j + 6 + sel];
                uint32 q0 = GATH(i0), q1 = GATH(i1), q2 = GATH(i2), q3 = GATH(i3);
                PROC(q0) PROC(q1) PROC(q2) PROC(q3)
            }
            for (; j + 2 <= je; j += 2) {
                int i0 = slds[j + sel];
                uint32 q0 = GATH(i0);
                PROC(q0)
            }
            if (j < je) {                        // odd final edge: low half only
                int i0 = slds[j];
                uint32 q0 = GATH(i0);
                float a0 = bf2f((unsigned short)(q0 & 0xffff));
                float a1 = bf2f((unsigned short)(q0 >> 16));
                float dd = half_sum_sel(fmaf(a1, hd1, a0 * hd0), false);
                if (!hi) {
                    acc0 = fmaf(dd, a0, acc0);
                    acc1 = fmaf(dd, a1, acc1);
                }
            }

            acc0 += __shfl_xor(acc0, 32, 64);
            acc1 += __shfl_xor(acc1, 32, 64);

            if (!hi) {
                float r0, r1;
                if (je > jb) { r0 = acc0 * c; r1 = acc1 * c; }
                else         { r0 = hd0;      r1 = hd1;      }
                *(float2*)(out + (size_t)node * OUT_F + half * 2) = make_float2(r0, r1);
            }
        }
    } else {
        // ---- fallback (correctness only; not expected for uniform dst) ----
#pragma unroll 1
        for (int k = 0; k < 8; ++k) {
            int n    = wid + 8 * k;
            int node = node0 + n;
            if (node >= N) continue;

            uint32 hd2 = *(const uint32*)(hpb + (size_t)node * OUT_F + half * 2);
            float hd0 = bf2f((unsigned short)(hd2 & 0xffff));
            float hd1 = bf2f((unsigned short)(hd2 >> 16));

            float acc0 = 0.f, acc1 = 0.f;
            int deg = 0;
            for (int p = 0; p < PART_BLOCKS; ++p) {
                int bb = segb[p], ee = bb + slen[p];
                for (int i = bb; i < ee; ++i) {
                    uint32 pr = pairs[i];
                    if ((int)(pr >> 26) == n) {
                        ++deg;
                        uint32 q0 = GATH((int)(pr & 0x3FFFFFFu));
                        float a0 = bf2f((unsigned short)(q0 & 0xffff));
                        float a1 = bf2f((unsigned short)(q0 >> 16));
                        float dd = half_sum_sel(fmaf(a1, hd1, a0 * hd0), false);
                        if (!hi) {
                            acc0 = fmaf(dd, a0, acc0);
                            acc1 = fmaf(dd, a1, acc1);
                        }
                    }
                }
            }
            acc0 += __shfl_xor(acc0, 32, 64);
            acc1 += __shfl_xor(acc1, 32, 64);
            if (!hi) {
                float r0, r1;
                if (deg > 0) { r0 = acc0 * c; r1 = acc1 * c; }
                else         { r0 = hd0;      r1 = hd1;      }
                *(float2*)(out + (size_t)node * OUT_F + half * 2) = make_float2(r0, r1);
            }
        }
    }
}

extern "C" void kernel_launch(void* const* d_in, const int* in_sizes, int n_in,
                              void* d_out, int out_size, void* d_ws, size_t ws_size,
                              hipStream_t stream) {
    const float* h    = (const float*)d_in[0];
    const float* w    = (const float*)d_in[1];
    const float* attw = (const float*)d_in[2];
    const int*   src  = (const int*)d_in[3];
    const int*   dst  = (const int*)d_in[4];

    int N = in_sizes[0] / IN_F;
    int E = in_sizes[3];
    int NB = (N + 63) >> 6;    // 782 for N=50000 (NB <= NBKT_MAX)
    int ngemm = (N + 63) / 64;

    float* out = (float*)d_out;

    char* p = (char*)d_ws;
    unsigned short* hpb = (unsigned short*)p;  p += (size_t)N * OUT_F * sizeof(unsigned short);
    int* tbl      = (int*)p;                   p += (size_t)PART_BLOCKS * (NBKT_MAX + 1) * sizeof(int);
    uint32* pairs = (uint32*)p;

    // no memset needed: all global scratch is fully written before being read
    gemm_part_kernel<<<PART_BLOCKS + ngemm, 256, 0, stream>>>(h, w, hpb, N,
                                                              src, dst, tbl, pairs, E, NB);

    accum_kernel<<<NB, 512, 0, stream>>>(hpb, pairs, tbl, attw, out, N, NB);
}

// Round 14
// 138.824 us; speedup vs baseline: 1.6941x; 1.0651x over previous
//
#include <hip/hip_runtime.h>

#define IN_F 256
#define OUT_F 64
#define NBKT_MAX 1024          // buckets of 64 dst nodes; supports N <= 65536
#define PART_BLOCKS 128
#define CAP 3072               // LDS edge capacity per bucket (mean ~1023, max ~1150)

typedef __attribute__((ext_vector_type(8))) short short8;
typedef __attribute__((ext_vector_type(4))) float f32x4;
typedef unsigned int uint32;

#define AS_I(f) __builtin_bit_cast(int, f)
#define AS_F(i) __builtin_bit_cast(float, i)
#define DPP_ADD(v, ctrl, rmask) \
    v += AS_F(__builtin_amdgcn_update_dpp(0, AS_I(v), ctrl, rmask, 0xf, true))

// Per-half (32-lane) sum: row_shr 1/2/4/8 + row_bcast:15 -> lane31 = low-half
// sum, lane63 = high-half sum. Select by half. Pure VALU pipe (DPP).
__device__ __forceinline__ float half_sum_sel(float p, bool hi) {
    DPP_ADD(p, 0x111, 0xf);
    DPP_ADD(p, 0x112, 0xf);
    DPP_ADD(p, 0x114, 0xf);
    DPP_ADD(p, 0x118, 0xf);
    DPP_ADD(p, 0x142, 0xa);
    float dlo = AS_F(__builtin_amdgcn_readlane(AS_I(p), 31));
    float dhi = AS_F(__builtin_amdgcn_readlane(AS_I(p), 63));
    return hi ? dhi : dlo;
}

__device__ __forceinline__ unsigned short f2bf(float f) {  // RNE f32->bf16
    uint32 u = __builtin_bit_cast(uint32, f);
    u += 0x7fffu + ((u >> 16) & 1u);
    return (unsigned short)(u >> 16);
}
__device__ __forceinline__ float bf2f(unsigned short s) {
    return __builtin_bit_cast(float, (uint32)s << 16);
}

// ---------------------------------------------------------------------------
// FUSED gemm + segment-table partition, 512 thr (8 waves).
// Blocks [0, PART_BLOCKS): partition own edge chunk into bucket-grouped runs
//   in the block's OWN region of pairs + segment table row tbl[p][b].
//   512 threads halve the pass iterations vs R13 (the serial chain).
// Blocks [PART_BLOCKS, ...): MFMA gemm, 128 rows/block (8 waves x 16 rows) --
//   halves block count and redundant w-staging traffic vs R13's 64-row blocks.
// ---------------------------------------------------------------------------
__global__ __launch_bounds__(512) void gemm_part_kernel(const float* __restrict__ h,
                                                        const float* __restrict__ w,
                                                        unsigned short* __restrict__ hpb,
                                                        int N,
                                                        const int* __restrict__ src,
                                                        const int* __restrict__ dst,
                                                        int* __restrict__ tbl,
                                                        uint32* __restrict__ pairs,
                                                        int E, int NB) {
    __shared__ char smem[32768];          // union: lcnt (partition) / wfrag (gemm)
    __shared__ int wsum[8];
    int b = blockIdx.x, t = threadIdx.x;

    if (b < PART_BLOCKS) {
        // ---- partition path ----
        int* lcnt = (int*)smem;           // counts, then chunk-relative cursors
        int lane = t & 63, wid = t >> 6;
        int chunk = (E + PART_BLOCKS - 1) / PART_BLOCKS;
        int s0 = b * chunk, s1 = min(E, s0 + chunk);

        for (int i = t; i < NB; i += 512) lcnt[i] = 0;
        __syncthreads();
        for (int e = s0 + t; e < s1; e += 512)
            atomicAdd(&lcnt[dst[e] >> 6], 1);
        __syncthreads();

        // exclusive scan of lcnt (2 consecutive values/thread, scalar locals)
        int i0 = t * 2;
        int x0 = (i0     < NB) ? lcnt[i0]     : 0;
        int x1 = (i0 + 1 < NB) ? lcnt[i0 + 1] : 0;
        int s  = x0 + x1;
        int xs = s;
#pragma unroll
        for (int off = 1; off < 64; off <<= 1) {
            int y = __shfl_up(xs, off, 64);
            if (lane >= off) xs += y;
        }
        if (lane == 63) wsum[wid] = xs;
        __syncthreads();                  // all lcnt reads done before overwrite
        int basew = 0;
        for (int k = 0; k < wid; ++k) basew += wsum[k];
        int toff = basew + xs - s;

        int* trow = tbl + (size_t)b * (NB + 1);
        if (i0     < NB) { trow[i0]     = s0 + toff;      lcnt[i0]     = toff;      }
        if (i0 + 1 < NB) { trow[i0 + 1] = s0 + toff + x0; lcnt[i0 + 1] = toff + x0; }
        if (t == 0) trow[NB] = s1;
        __syncthreads();

        // place pass: lcnt is now the per-bucket cursor (chunk-relative)
        for (int e = s0 + t; e < s1; e += 512) {
            int d  = dst[e];
            int bk = d >> 6;
            int idx = atomicAdd(&lcnt[bk], 1);
            pairs[s0 + idx] = (uint32)src[e] | ((uint32)(d & 63) << 26);
        }
        return;
    }

    // ---- gemm path: 128 rows/block, 8 waves x 16 rows ----
    int gb = b - PART_BLOCKS;
    short8* wfrag = (short8*)smem;        // 2048 slots * 16B = 32 KB
    for (int slot = t; slot < 2048; slot += 512) {
        int kb = slot >> 6, n = slot & 63;
        short8 v;
#pragma unroll
        for (int jj = 0; jj < 8; ++jj)
            v[jj] = (short)f2bf(w[(size_t)(kb * 8 + jj) * OUT_F + n]);
        wfrag[slot] = v;
    }
    __syncthreads();

    int wave = t >> 6, lane = t & 63;
    int n16  = lane & 15, quad = lane >> 4;
    int base = gb * 128 + wave * 16;
    int arow_i = base + n16; if (arow_i >= N) arow_i = N - 1;
    const float* arow = h + (size_t)arow_i * IN_F;

    f32x4 acc[4];
#pragma unroll
    for (int ct = 0; ct < 4; ++ct) acc[ct] = (f32x4){0.f, 0.f, 0.f, 0.f};

#pragma unroll
    for (int ks = 0; ks < 8; ++ks) {
        int k0 = ks * 32;
        float4 a0 = *(const float4*)(arow + k0 + quad * 8);
        float4 a1 = *(const float4*)(arow + k0 + quad * 8 + 4);
        short8 af;
        af[0] = (short)f2bf(a0.x); af[1] = (short)f2bf(a0.y);
        af[2] = (short)f2bf(a0.z); af[3] = (short)f2bf(a0.w);
        af[4] = (short)f2bf(a1.x); af[5] = (short)f2bf(a1.y);
        af[6] = (short)f2bf(a1.z); af[7] = (short)f2bf(a1.w);
        int kb = ks * 4 + quad;
#pragma unroll
        for (int ct = 0; ct < 4; ++ct) {
            short8 bf = wfrag[kb * 64 + ct * 16 + n16];
            acc[ct] = __builtin_amdgcn_mfma_f32_16x16x32_bf16(af, bf, acc[ct], 0, 0, 0);
        }
    }

#pragma unroll
    for (int ct = 0; ct < 4; ++ct) {
#pragma unroll
        for (int r = 0; r < 4; ++r) {
            int ro = base + quad * 4 + r;
            if (ro < N) hpb[(size_t)ro * OUT_F + ct * 16 + n16] = f2bf(acc[ct][r]);
        }
    }
}

// ---------------------------------------------------------------------------
// FUSED gather+sort+accumulate: block = bucket of 64 dst nodes, 512 thr.
// 1) read 128 segment descriptors (tbl column), wave-scan lengths -> psum;
// 2) stage bucket's edges from 128 pair-runs into LDS (binary search psum);
// 3) LDS counting sort by dstLocal; 4) per-node wave accumulate: lanes 0-31 =
//    even edge, 32-63 = odd edge, lane = 2 bf16 features -> one dword gather
//    serves two edge rows; 16-edge batches, ALL SCALAR STATE (R10 lesson).
// Fallback nE > CAP: filtered scan over segments (correctness only).
// ---------------------------------------------------------------------------
#define GATH(S) (*(const uint32*)(hpb + (size_t)(S) * OUT_F + half * 2))
#define PROC(Q) { float a0 = bf2f((unsigned short)((Q) & 0xffff));            \
                  float a1 = bf2f((unsigned short)((Q) >> 16));               \
                  float dd = half_sum_sel(fmaf(a1, hd1, a0 * hd0), hi);       \
                  acc0 = fmaf(dd, a0, acc0); acc1 = fmaf(dd, a1, acc1); }

__global__ __launch_bounds__(512) void accum_kernel(const unsigned short* __restrict__ hpb,
                                                    const uint32* __restrict__ pairs,
                                                    const int* __restrict__ tbl,
                                                    const float* __restrict__ attw,
                                                    float* __restrict__ out, int N, int NB) {
    __shared__ uint32 sraw[CAP];
    __shared__ int slds[CAP];
    __shared__ int segb[PART_BLOCKS], slen[PART_BLOCKS], psum[PART_BLOCKS + 1];
    __shared__ int bin[64], excl[65], cur[64];

    int b = blockIdx.x, t = threadIdx.x;
    int wid = t >> 6, lane = t & 63;
    int half = lane & 31;
    bool hi  = lane >= 32;
    int node0 = b * 64;

    // ---- segment descriptors ----
    if (t < PART_BLOCKS) {
        const int* trow = tbl + (size_t)t * (NB + 1);
        int b0 = trow[b];
        segb[t] = b0;
        slen[t] = trow[b + 1] - b0;
    }
    __syncthreads();
    if (wid == 0) {                       // wave-0 exclusive scan of 128 lengths
        int l0 = slen[lane * 2], l1 = slen[lane * 2 + 1];
        int s = l0 + l1, xs = s;
#pragma unroll
        for (int off = 1; off < 64; off <<= 1) {
            int y = __shfl_up(xs, off, 64);
            if (lane >= off) xs += y;
        }
        int ex = xs - s;
        psum[lane * 2]     = ex;
        psum[lane * 2 + 1] = ex + l0;
        if (lane == 63) psum[PART_BLOCKS] = xs;
    }
    __syncthreads();
    int nE = psum[PART_BLOCKS];

    float c = 0.f;
#pragma unroll
    for (int i = 0; i < 8; ++i) c += attw[i];

    if (nE <= CAP) {
        // ---- stage: binary search psum for segment of each edge ----
        for (int i = t; i < nE; i += 512) {
            int lo = 0, hh = PART_BLOCKS - 1;
#pragma unroll
            for (int it = 0; it < 7; ++it) {   // 2^7 = 128
                int mid = (lo + hh + 1) >> 1;
                if (psum[mid] <= i) lo = mid; else hh = mid - 1;
            }
            sraw[i] = pairs[segb[lo] + (i - psum[lo])];
        }
        // ---- counting sort in LDS ----
        if (t < 64) bin[t] = 0;
        __syncthreads();
        for (int i = t; i < nE; i += 512)
            atomicAdd(&bin[sraw[i] >> 26], 1);
        __syncthreads();
        if (t < 64) {
            int v = bin[t], x = v;
#pragma unroll
            for (int off = 1; off < 64; off <<= 1) {
                int y = __shfl_up(x, off, 64);
                if (t >= off) x += y;
            }
            excl[t] = x - v;
            cur[t]  = x - v;
            if (t == 63) excl[64] = x;
        }
        __syncthreads();
        for (int i = t; i < nE; i += 512) {
            uint32 p = sraw[i];
            int pos = atomicAdd(&cur[(int)(p >> 26)], 1);
            slds[pos] = (int)(p & 0x3FFFFFFu);
        }
        __syncthreads();

        // ---- accumulate: wave wid handles nodes wid + 8k ----
#pragma unroll 1
        for (int k = 0; k < 8; ++k) {
            int n    = wid + 8 * k;
            int node = node0 + n;
            if (node >= N) continue;

            int jb = excl[n], je = excl[n + 1];

            uint32 hd2 = *(const uint32*)(hpb + (size_t)node * OUT_F + half * 2);
            float hd0 = bf2f((unsigned short)(hd2 & 0xffff));
            float hd1 = bf2f((unsigned short)(hd2 >> 16));

            float acc0 = 0.f, acc1 = 0.f;
            int j = jb;
            int sel = hi ? 1 : 0;

            for (; j + 16 <= je; j += 16) {      // 8 gathers = 16 edges in flight
                int i0 = slds[j + 0  + sel], i1 = slds[j + 2  + sel];
                int i2 = slds[j + 4  + sel], i3 = slds[j + 6  + sel];
                int i4 = slds[j + 8  + sel], i5 = slds[j + 10 + sel];
                int i6 = slds[j + 12 + sel], i7 = slds[j + 14 + sel];
                uint32 q0 = GATH(i0), q1 = GATH(i1), q2 = GATH(i2), q3 = GATH(i3);
                uint32 q4 = GATH(i4), q5 = GATH(i5), q6 = GATH(i6), q7 = GATH(i7);
                PROC(q0) PROC(q1) PROC(q2) PROC(q3)
                PROC(q4) PROC(q5) PROC(q6) PROC(q7)
            }
            for (; j + 8 <= je; j += 8) {        // 4 gathers = 8 edges
                int i0 = slds[j + 0 + sel], i1 = slds[j + 2 + sel];
                int i2 = slds[j + 4 + sel], i3 = slds[j + 6 + sel];
                uint32 q0 = GATH(i0), q1 = GATH(i1), q2 = GATH(i2), q3 = GATH(i3);
                PROC(q0) PROC(q1) PROC(q2) PROC(q3)
            }
            for (; j + 2 <= je; j += 2) {
                int i0 = slds[j + sel];
                uint32 q0 = GATH(i0);
                PROC(q0)
            }
            if (j < je) {                        // odd final edge: low half only
                int i0 = slds[j];
                uint32 q0 = GATH(i0);
                float a0 = bf2f((unsigned short)(q0 & 0xffff));
                float a1 = bf2f((unsigned short)(q0 >> 16));
                float dd = half_sum_sel(fmaf(a1, hd1, a0 * hd0), false);
                if (!hi) {
                    acc0 = fmaf(dd, a0, acc0);
                    acc1 = fmaf(dd, a1, acc1);
                }
            }

            acc0 += __shfl_xor(acc0, 32, 64);
            acc1 += __shfl_xor(acc1, 32, 64);

            if (!hi) {
                float r0, r1;
                if (je > jb) { r0 = acc0 * c; r1 = acc1 * c; }
                else         { r0 = hd0;      r1 = hd1;      }
                *(float2*)(out + (size_t)node * OUT_F + half * 2) = make_float2(r0, r1);
            }
        }
    } else {
        // ---- fallback (correctness only; not expected for uniform dst) ----
#pragma unroll 1
        for (int k = 0; k < 8; ++k) {
            int n    = wid + 8 * k;
            int node = node0 + n;
            if (node >= N) continue;

            uint32 hd2 = *(const uint32*)(hpb + (size_t)node * OUT_F + half * 2);
            float hd0 = bf2f((unsigned short)(hd2 & 0xffff));
            float hd1 = bf2f((unsigned short)(hd2 >> 16));

            float acc0 = 0.f, acc1 = 0.f;
            int deg = 0;
            for (int p = 0; p < PART_BLOCKS; ++p) {
                int bb = segb[p], ee = bb + slen[p];
                for (int i = bb; i < ee; ++i) {
                    uint32 pr = pairs[i];
                    if ((int)(pr >> 26) == n) {
                        ++deg;
                        uint32 q0 = GATH((int)(pr & 0x3FFFFFFu));
                        float a0 = bf2f((unsigned short)(q0 & 0xffff));
                        float a1 = bf2f((unsigned short)(q0 >> 16));
                        float dd = half_sum_sel(fmaf(a1, hd1, a0 * hd0), false);
                        if (!hi) {
                            acc0 = fmaf(dd, a0, acc0);
                            acc1 = fmaf(dd, a1, acc1);
                        }
                    }
                }
            }
            acc0 += __shfl_xor(acc0, 32, 64);
            acc1 += __shfl_xor(acc1, 32, 64);
            if (!hi) {
                float r0, r1;
                if (deg > 0) { r0 = acc0 * c; r1 = acc1 * c; }
                else         { r0 = hd0;      r1 = hd1;      }
                *(float2*)(out + (size_t)node * OUT_F + half * 2) = make_float2(r0, r1);
            }
        }
    }
}

extern "C" void kernel_launch(void* const* d_in, const int* in_sizes, int n_in,
                              void* d_out, int out_size, void* d_ws, size_t ws_size,
                              hipStream_t stream) {
    const float* h    = (const float*)d_in[0];
    const float* w    = (const float*)d_in[1];
    const float* attw = (const float*)d_in[2];
    const int*   src  = (const int*)d_in[3];
    const int*   dst  = (const int*)d_in[4];

    int N = in_sizes[0] / IN_F;
    int E = in_sizes[3];
    int NB = (N + 63) >> 6;    // 782 for N=50000 (NB <= NBKT_MAX)
    int ngemm = (N + 127) / 128;

    float* out = (float*)d_out;

    char* p = (char*)d_ws;
    unsigned short* hpb = (unsigned short*)p;  p += (size_t)N * OUT_F * sizeof(unsigned short);
    int* tbl      = (int*)p;                   p += (size_t)PART_BLOCKS * (NBKT_MAX + 1) * sizeof(int);
    uint32* pairs = (uint32*)p;

    // no memset needed: all global scratch is fully written before being read
    gemm_part_kernel<<<PART_BLOCKS + ngemm, 512, 0, stream>>>(h, w, hpb, N,
                                                              src, dst, tbl, pairs, E, NB);

    accum_kernel<<<NB, 512, 0, stream>>>(hpb, pairs, tbl, attw, out, N, NB);
}